// Round 1
// baseline (530.933 us; speedup 1.0000x reference)
//
#include <hip/hip_runtime.h>
#include <hip/hip_bf16.h>
#include <stdint.h>

// ---- problem constants ----
#define TOKENS 4096      // B*N = 2*2048
#define SEQ    2048
#define CMODEL 1024
#define HEADS  16
#define HDIM   64
#define DFF    4096

typedef __attribute__((ext_vector_type(8))) short     short8;
typedef __attribute__((ext_vector_type(8))) unsigned short ushort8;
typedef __attribute__((ext_vector_type(4))) unsigned short ushort4v;
typedef __attribute__((ext_vector_type(4))) float     f32x4;

typedef const __attribute__((address_space(1))) void gbl_cvoid;
typedef __attribute__((address_space(3))) void lds_void;

__device__ inline unsigned short f2bf(float f) {
  unsigned int u = __builtin_bit_cast(unsigned int, f);
  u += 0x7fffu + ((u >> 16) & 1u);
  return (unsigned short)(u >> 16);
}
__device__ inline float bf2f(unsigned short h) {
  unsigned int u = ((unsigned int)h) << 16;
  return __builtin_bit_cast(float, u);
}

__device__ inline void gload_lds16(const unsigned short* g, unsigned short* lds) {
  __builtin_amdgcn_global_load_lds((gbl_cvoid*)g, (lds_void*)lds, 16, 0, 0);
}

// ---------------- f32 -> bf16 convert (8 elems/thread) ----------------
__global__ __launch_bounds__(256) void k_cvt(const float* __restrict__ in,
                                             unsigned short* __restrict__ out, int n8) {
  int i = blockIdx.x * 256 + threadIdx.x;
  if (i >= n8) return;
  const float4* p = (const float4*)in + 2 * (size_t)i;
  float4 a = p[0], b = p[1];
  ushort8 o;
  o[0] = f2bf(a.x); o[1] = f2bf(a.y); o[2] = f2bf(a.z); o[3] = f2bf(a.w);
  o[4] = f2bf(b.x); o[5] = f2bf(b.y); o[6] = f2bf(b.z); o[7] = f2bf(b.w);
  ((ushort8*)out)[i] = o;
}

// ---------------- bf16 BT-GEMM: C[M,N] = A[M,K] @ B[N,K]^T ----------------
// 128x128 tile, BK=32, 4 waves (2x2), each wave 64x64 = 4x4 frags of 16x16x32.
// EPI: 0 = bf16 plain; 1 = f32 (+bias +res_f32); 2 = bf16 relu(+bias); 3 = f32 (+bias +res_bf16)
template<int EPI>
__global__ __launch_bounds__(256) void k_gemm_bt(
    const unsigned short* __restrict__ A,   // [M,K] bf16
    const unsigned short* __restrict__ B,   // [N,K] bf16 (BT)
    unsigned short* __restrict__ Cb,
    float* __restrict__ Cf,
    const float* __restrict__ bias,
    const float* __restrict__ resf,
    const unsigned short* __restrict__ resb,
    int M, int N, int K)
{
  __shared__ unsigned short As[128 * 32];
  __shared__ unsigned short Bs[128 * 32];
  const int t = threadIdx.x;
  const int lane = t & 63;
  const int w = t >> 6;
  const int wr = w >> 1, wc = w & 1;
  const int m0 = blockIdx.y * 128, n0 = blockIdx.x * 128;

  // staging map: wave-instr ii = w*2+j covers flat elems ii*512 .. +511 (lane*8 each)
  const int e0 = w * 1024 + lane * 8;
  const int e1 = e0 + 512;
  const int r0 = e0 >> 5, c0 = e0 & 31;
  const int r1 = e1 >> 5, c1 = e1 & 31;

  f32x4 acc[4][4] = {};
  const int lr = lane & 15, lh = lane >> 4;
  const int nkt = K >> 5;
  for (int kt = 0; kt < nkt; ++kt) {
    const int kb = kt << 5;
    gload_lds16(A + (size_t)(m0 + r0) * K + kb + c0, &As[w * 1024]);
    gload_lds16(A + (size_t)(m0 + r1) * K + kb + c1, &As[w * 1024 + 512]);
    gload_lds16(B + (size_t)(n0 + r0) * K + kb + c0, &Bs[w * 1024]);
    gload_lds16(B + (size_t)(n0 + r1) * K + kb + c1, &Bs[w * 1024 + 512]);
    __syncthreads();
    short8 af[4], bg[4];
    for (int m = 0; m < 4; ++m)
      af[m] = *(const short8*)&As[(wr * 64 + m * 16 + lr) * 32 + lh * 8];
    for (int n = 0; n < 4; ++n)
      bg[n] = *(const short8*)&Bs[(wc * 64 + n * 16 + lr) * 32 + lh * 8];
    for (int m = 0; m < 4; ++m)
      for (int n = 0; n < 4; ++n)
        acc[m][n] = __builtin_amdgcn_mfma_f32_16x16x32_bf16(af[m], bg[n], acc[m][n], 0, 0, 0);
    __syncthreads();
  }

  for (int m = 0; m < 4; ++m) {
    for (int n = 0; n < 4; ++n) {
      const int col = n0 + wc * 64 + n * 16 + lr;
      for (int r = 0; r < 4; ++r) {
        const int row = m0 + wr * 64 + m * 16 + lh * 4 + r;
        const size_t idx = (size_t)row * N + col;
        float v = acc[m][n][r];
        if (EPI == 0) {
          Cb[idx] = f2bf(v);
        } else if (EPI == 1) {
          Cf[idx] = v + bias[col] + resf[idx];
        } else if (EPI == 2) {
          v += bias[col];
          Cb[idx] = f2bf(v > 0.f ? v : 0.f);
        } else {
          Cf[idx] = v + bias[col] + bf2f(resb[idx]);
        }
      }
    }
  }
}

// ---------------- flash attention: QBLK=64, KVBLK=64, 4 waves ----------------
// qkv layout: [token][3*1024], col = c3*1024 + h*64 + d
__global__ __launch_bounds__(256) void k_attn(
    const unsigned short* __restrict__ qkv,
    unsigned short* __restrict__ outb)   // [token][1024]
{
  __shared__ unsigned short Qs[64 * 64];
  __shared__ unsigned short Ks[64 * 64];
  __shared__ unsigned short Vt[64 * 64];   // transposed: Vt[d][kv]
  __shared__ unsigned short Ps[4][16 * 64];

  const int t = threadIdx.x, lane = t & 63, w = t >> 6;
  const int bh = blockIdx.y;
  const int b = bh >> 4, h = bh & 15;
  const int q0 = blockIdx.x * 64;
  const size_t tokbase = (size_t)b * SEQ;
  const int qoff = h * 64, koff = 1024 + h * 64, voff = 2048 + h * 64;
  const int lr = lane & 15, lh = lane >> 4;

  // stage Q once
  {
    const int e0 = w * 1024 + lane * 8, e1 = e0 + 512;
    gload_lds16(qkv + (tokbase + q0 + (e0 >> 6)) * 3072 + qoff + (e0 & 63), &Qs[w * 1024]);
    gload_lds16(qkv + (tokbase + q0 + (e1 >> 6)) * 3072 + qoff + (e1 & 63), &Qs[w * 1024 + 512]);
  }

  float m_run[4], l_run[4];
  for (int r = 0; r < 4; ++r) { m_run[r] = -1e30f; l_run[r] = 0.f; }
  f32x4 oacc[4] = {};
  const float SCL = 0.125f * 1.44269504089f;  // head_scale * log2(e)

  for (int kt = 0; kt < SEQ / 64; ++kt) {
    __syncthreads();   // prior iter reads done (also Q-load drain at kt=0)
    // stage K (natural, BT format for S = Q @ K^T)
    {
      const int e0 = w * 1024 + lane * 8, e1 = e0 + 512;
      gload_lds16(qkv + (tokbase + kt * 64 + (e0 >> 6)) * 3072 + koff + (e0 & 63), &Ks[w * 1024]);
      gload_lds16(qkv + (tokbase + kt * 64 + (e1 >> 6)) * 3072 + koff + (e1 & 63), &Ks[w * 1024 + 512]);
    }
    // stage V transposed (vector global read, scalar LDS writes)
    {
      const int kvr = t >> 2;
      const int d0 = (t & 3) * 16;
      const unsigned short* vsrc = qkv + (tokbase + kt * 64 + kvr) * 3072 + voff + d0;
      ushort8 v0 = *(const ushort8*)vsrc;
      ushort8 v1 = *(const ushort8*)(vsrc + 8);
      for (int i = 0; i < 8; ++i) Vt[(d0 + i) * 64 + kvr] = v0[i];
      for (int i = 0; i < 8; ++i) Vt[(d0 + 8 + i) * 64 + kvr] = v1[i];
    }
    __syncthreads();

    // S = Q @ K^T  (wave w owns q-rows w*16..w*16+15)
    short8 aq0 = *(const short8*)&Qs[(w * 16 + lr) * 64 + lh * 8];
    short8 aq1 = *(const short8*)&Qs[(w * 16 + lr) * 64 + 32 + lh * 8];
    f32x4 sacc[4] = {};
    for (int nf = 0; nf < 4; ++nf) {
      short8 bk0 = *(const short8*)&Ks[(nf * 16 + lr) * 64 + lh * 8];
      short8 bk1 = *(const short8*)&Ks[(nf * 16 + lr) * 64 + 32 + lh * 8];
      sacc[nf] = __builtin_amdgcn_mfma_f32_16x16x32_bf16(aq0, bk0, sacc[nf], 0, 0, 0);
      sacc[nf] = __builtin_amdgcn_mfma_f32_16x16x32_bf16(aq1, bk1, sacc[nf], 0, 0, 0);
    }

    // online softmax per q-row (rows lh*4+r, replicated across the 16 lr lanes)
    float p[4][4];
    for (int r = 0; r < 4; ++r) {
      float mx = fmaxf(fmaxf(sacc[0][r], sacc[1][r]), fmaxf(sacc[2][r], sacc[3][r])) * SCL;
      for (int off = 1; off < 16; off <<= 1) mx = fmaxf(mx, __shfl_xor(mx, off));
      float mnew = fmaxf(m_run[r], mx);
      float alpha = exp2f(m_run[r] - mnew);
      m_run[r] = mnew;
      float rs = 0.f;
      for (int nf = 0; nf < 4; ++nf) {
        float pv = exp2f(sacc[nf][r] * SCL - mnew);
        p[nf][r] = pv;
        rs += pv;
      }
      for (int off = 1; off < 16; off <<= 1) rs += __shfl_xor(rs, off);
      l_run[r] = l_run[r] * alpha + rs;
      for (int nf = 0; nf < 4; ++nf) oacc[nf][r] *= alpha;
    }

    // P -> LDS strip (per-wave private), then PV
    for (int nf = 0; nf < 4; ++nf)
      for (int r = 0; r < 4; ++r)
        Ps[w][(lh * 4 + r) * 64 + nf * 16 + lr] = f2bf(p[nf][r]);

    short8 pa0 = *(const short8*)&Ps[w][lr * 64 + lh * 8];
    short8 pa1 = *(const short8*)&Ps[w][lr * 64 + 32 + lh * 8];
    for (int nf = 0; nf < 4; ++nf) {
      short8 vb0 = *(const short8*)&Vt[(nf * 16 + lr) * 64 + lh * 8];
      short8 vb1 = *(const short8*)&Vt[(nf * 16 + lr) * 64 + 32 + lh * 8];
      oacc[nf] = __builtin_amdgcn_mfma_f32_16x16x32_bf16(pa0, vb0, oacc[nf], 0, 0, 0);
      oacc[nf] = __builtin_amdgcn_mfma_f32_16x16x32_bf16(pa1, vb1, oacc[nf], 0, 0, 0);
    }
  }

  // epilogue: O / l
  for (int nf = 0; nf < 4; ++nf)
    for (int r = 0; r < 4; ++r) {
      const int row = q0 + w * 16 + lh * 4 + r;
      const int col = h * 64 + nf * 16 + lr;
      outb[(tokbase + row) * (size_t)CMODEL + col] = f2bf(oacc[nf][r] / l_run[r]);
    }
}

// ---------------- LayerNorm over rows of 1024 ----------------
template<int OUT_BF>
__global__ __launch_bounds__(256) void k_ln(const float* __restrict__ in,
    const float* __restrict__ g, const float* __restrict__ b,
    float* __restrict__ outf, unsigned short* __restrict__ outb)
{
  const int row = blockIdx.x;
  const int t = threadIdx.x;
  const float4* x4 = (const float4*)(in + (size_t)row * CMODEL);
  float4 v = x4[t];
  float s  = v.x + v.y + v.z + v.w;
  float s2 = v.x * v.x + v.y * v.y + v.z * v.z + v.w * v.w;
  for (int off = 32; off; off >>= 1) { s += __shfl_down(s, off); s2 += __shfl_down(s2, off); }
  __shared__ float red[8];
  __shared__ float stats[2];
  const int wv = t >> 6;
  if ((t & 63) == 0) { red[wv] = s; red[4 + wv] = s2; }
  __syncthreads();
  if (t == 0) {
    float ts  = red[0] + red[1] + red[2] + red[3];
    float ts2 = red[4] + red[5] + red[6] + red[7];
    float mu  = ts * (1.f / CMODEL);
    float var = ts2 * (1.f / CMODEL) - mu * mu;
    stats[0] = mu; stats[1] = rsqrtf(var + 1e-5f);
  }
  __syncthreads();
  const float mu = stats[0], rstd = stats[1];
  float4 gv = ((const float4*)g)[t];
  float4 bv = ((const float4*)b)[t];
  float o0 = (v.x - mu) * rstd * gv.x + bv.x;
  float o1 = (v.y - mu) * rstd * gv.y + bv.y;
  float o2 = (v.z - mu) * rstd * gv.z + bv.z;
  float o3 = (v.w - mu) * rstd * gv.w + bv.w;
  if (OUT_BF) {
    ushort4v o; o[0] = f2bf(o0); o[1] = f2bf(o1); o[2] = f2bf(o2); o[3] = f2bf(o3);
    ((ushort4v*)(outb + (size_t)row * CMODEL))[t] = o;
  } else {
    float4 o; o.x = o0; o.y = o1; o.z = o2; o.w = o3;
    ((float4*)(outf + (size_t)row * CMODEL))[t] = o;
  }
}

// ---------------- launch ----------------
extern "C" void kernel_launch(void* const* d_in, const int* in_sizes, int n_in,
                              void* d_out, int out_size, void* d_ws, size_t ws_size,
                              hipStream_t stream) {
  const float* src    = (const float*)d_in[0];
  const float* w_qkv  = (const float*)d_in[1];
  const float* w_proj = (const float*)d_in[2];
  const float* b_proj = (const float*)d_in[3];
  const float* w1     = (const float*)d_in[4];
  const float* b1     = (const float*)d_in[5];
  const float* w2     = (const float*)d_in[6];
  const float* b2     = (const float*)d_in[7];
  const float* g1     = (const float*)d_in[8];
  const float* be1    = (const float*)d_in[9];
  const float* g2     = (const float*)d_in[10];
  const float* be2    = (const float*)d_in[11];
  float* out = (float*)d_out;

  char* ws = (char*)d_ws;
  size_t off = 0;
  auto alloc = [&](size_t bytes) -> void* {
    void* p = ws + off;
    off += (bytes + 255) & ~(size_t)255;
    return p;
  };
  unsigned short* src_bf   = (unsigned short*)alloc((size_t)TOKENS * CMODEL * 2);
  unsigned short* wqkv_bf  = (unsigned short*)alloc((size_t)3 * CMODEL * CMODEL * 2);
  unsigned short* wproj_bf = (unsigned short*)alloc((size_t)CMODEL * CMODEL * 2);
  unsigned short* w1_bf    = (unsigned short*)alloc((size_t)DFF * CMODEL * 2);
  unsigned short* w2_bf    = (unsigned short*)alloc((size_t)CMODEL * DFF * 2);
  unsigned short* qkv_bf   = (unsigned short*)alloc((size_t)TOKENS * 3 * CMODEL * 2);
  unsigned short* attno_bf = (unsigned short*)alloc((size_t)TOKENS * CMODEL * 2);
  float*          z_f32    = (float*)alloc((size_t)TOKENS * CMODEL * 4);
  unsigned short* x_bf     = (unsigned short*)alloc((size_t)TOKENS * CMODEL * 2);
  unsigned short* h_bf     = (unsigned short*)alloc((size_t)TOKENS * DFF * 2);

  auto cvt = [&](const float* i, unsigned short* o, size_t n) {
    int n8 = (int)(n / 8);
    k_cvt<<<(n8 + 255) / 256, 256, 0, stream>>>(i, o, n8);
  };
  cvt(src,    src_bf,   (size_t)TOKENS * CMODEL);
  cvt(w_qkv,  wqkv_bf,  (size_t)3 * CMODEL * CMODEL);
  cvt(w_proj, wproj_bf, (size_t)CMODEL * CMODEL);
  cvt(w1,     w1_bf,    (size_t)DFF * CMODEL);
  cvt(w2,     w2_bf,    (size_t)CMODEL * DFF);

  // qkv = src @ w_qkv^T            [4096, 3072]
  k_gemm_bt<0><<<dim3(3072 / 128, TOKENS / 128), 256, 0, stream>>>(
      src_bf, wqkv_bf, qkv_bf, nullptr, nullptr, nullptr, nullptr, TOKENS, 3 * CMODEL, CMODEL);
  // attention -> attno             [4096, 1024]
  k_attn<<<dim3(SEQ / 64, 2 * HEADS), 256, 0, stream>>>(qkv_bf, attno_bf);
  // z = attno @ w_proj^T + b_proj + src   (f32)
  k_gemm_bt<1><<<dim3(CMODEL / 128, TOKENS / 128), 256, 0, stream>>>(
      attno_bf, wproj_bf, nullptr, z_f32, b_proj, src, nullptr, TOKENS, CMODEL, CMODEL);
  // x = LN1(z) -> bf16
  k_ln<1><<<TOKENS, 256, 0, stream>>>(z_f32, g1, be1, nullptr, x_bf);
  // h = relu(x @ w1^T + b1) -> bf16       [4096, 4096]
  k_gemm_bt<2><<<dim3(DFF / 128, TOKENS / 128), 256, 0, stream>>>(
      x_bf, w1_bf, h_bf, nullptr, b1, nullptr, nullptr, TOKENS, DFF, CMODEL);
  // z = h @ w2^T + b2 + x  (f32)
  k_gemm_bt<3><<<dim3(CMODEL / 128, TOKENS / 128), 256, 0, stream>>>(
      h_bf, w2_bf, nullptr, z_f32, b2, nullptr, x_bf, TOKENS, CMODEL, DFF);
  // out = LN2(z)
  k_ln<0><<<TOKENS, 256, 0, stream>>>(z_f32, g2, be2, out, nullptr);
}

// Round 2
// 520.286 us; speedup vs baseline: 1.0205x; 1.0205x over previous
//
#include <hip/hip_runtime.h>
#include <hip/hip_bf16.h>
#include <stdint.h>

// ---- problem constants ----
#define TOKENS 4096      // B*N = 2*2048
#define SEQ    2048
#define CMODEL 1024
#define HEADS  16
#define HDIM   64
#define DFF    4096

typedef __attribute__((ext_vector_type(8))) short     short8;
typedef __attribute__((ext_vector_type(8))) unsigned short ushort8;
typedef __attribute__((ext_vector_type(4))) unsigned short ushort4v;
typedef __attribute__((ext_vector_type(4))) float     f32x4;

typedef const __attribute__((address_space(1))) void gbl_cvoid;
typedef __attribute__((address_space(3))) void lds_void;

__device__ inline unsigned short f2bf(float f) {
  unsigned int u = __builtin_bit_cast(unsigned int, f);
  u += 0x7fffu + ((u >> 16) & 1u);
  return (unsigned short)(u >> 16);
}
__device__ inline float bf2f(unsigned short h) {
  unsigned int u = ((unsigned int)h) << 16;
  return __builtin_bit_cast(float, u);
}

__device__ inline void gload_lds16(const unsigned short* g, unsigned short* lds) {
  __builtin_amdgcn_global_load_lds((gbl_cvoid*)g, (lds_void*)lds, 16, 0, 0);
}

// ---------------- f32 -> bf16 convert (8 elems/thread) ----------------
__global__ __launch_bounds__(256) void k_cvt(const float* __restrict__ in,
                                             unsigned short* __restrict__ out, int n8) {
  int i = blockIdx.x * 256 + threadIdx.x;
  if (i >= n8) return;
  const float4* p = (const float4*)in + 2 * (size_t)i;
  float4 a = p[0], b = p[1];
  ushort8 o;
  o[0] = f2bf(a.x); o[1] = f2bf(a.y); o[2] = f2bf(a.z); o[3] = f2bf(a.w);
  o[4] = f2bf(b.x); o[5] = f2bf(b.y); o[6] = f2bf(b.z); o[7] = f2bf(b.w);
  ((ushort8*)out)[i] = o;
}

// ---------------- bf16 BT-GEMM: C[M,N] = A[M,K] @ B[N,K]^T ----------------
// 128x128 tile, BK=32, 4 waves (2x2), each wave 64x64 = 4x4 frags of 16x16x32.
// EPI: 0 = bf16 plain; 1 = f32 (+bias +res_f32); 2 = bf16 relu(+bias); 3 = f32 (+bias +res_bf16)
template<int EPI>
__global__ __launch_bounds__(256) void k_gemm_bt(
    const unsigned short* __restrict__ A,   // [M,K] bf16
    const unsigned short* __restrict__ B,   // [N,K] bf16 (BT)
    unsigned short* __restrict__ Cb,
    float* __restrict__ Cf,
    const float* __restrict__ bias,
    const float* __restrict__ resf,
    const unsigned short* __restrict__ resb,
    int M, int N, int K)
{
  __shared__ unsigned short As[128 * 32];
  __shared__ unsigned short Bs[128 * 32];
  const int t = threadIdx.x;
  const int lane = t & 63;
  const int w = t >> 6;
  const int wr = w >> 1, wc = w & 1;
  const int m0 = blockIdx.y * 128, n0 = blockIdx.x * 128;

  // staging map: wave-instr ii = w*2+j covers flat elems ii*512 .. +511 (lane*8 each)
  const int e0 = w * 1024 + lane * 8;
  const int e1 = e0 + 512;
  const int r0 = e0 >> 5, c0 = e0 & 31;
  const int r1 = e1 >> 5, c1 = e1 & 31;

  f32x4 acc[4][4] = {};
  const int lr = lane & 15, lh = lane >> 4;
  const int nkt = K >> 5;
  for (int kt = 0; kt < nkt; ++kt) {
    const int kb = kt << 5;
    gload_lds16(A + (size_t)(m0 + r0) * K + kb + c0, &As[w * 1024]);
    gload_lds16(A + (size_t)(m0 + r1) * K + kb + c1, &As[w * 1024 + 512]);
    gload_lds16(B + (size_t)(n0 + r0) * K + kb + c0, &Bs[w * 1024]);
    gload_lds16(B + (size_t)(n0 + r1) * K + kb + c1, &Bs[w * 1024 + 512]);
    __syncthreads();
    short8 af[4], bg[4];
    for (int m = 0; m < 4; ++m)
      af[m] = *(const short8*)&As[(wr * 64 + m * 16 + lr) * 32 + lh * 8];
    for (int n = 0; n < 4; ++n)
      bg[n] = *(const short8*)&Bs[(wc * 64 + n * 16 + lr) * 32 + lh * 8];
    for (int m = 0; m < 4; ++m)
      for (int n = 0; n < 4; ++n)
        acc[m][n] = __builtin_amdgcn_mfma_f32_16x16x32_bf16(af[m], bg[n], acc[m][n], 0, 0, 0);
    __syncthreads();
  }

  for (int m = 0; m < 4; ++m) {
    for (int n = 0; n < 4; ++n) {
      const int col = n0 + wc * 64 + n * 16 + lr;
      for (int r = 0; r < 4; ++r) {
        const int row = m0 + wr * 64 + m * 16 + lh * 4 + r;
        const size_t idx = (size_t)row * N + col;
        float v = acc[m][n][r];
        if (EPI == 0) {
          Cb[idx] = f2bf(v);
        } else if (EPI == 1) {
          Cf[idx] = v + bias[col] + resf[idx];
        } else if (EPI == 2) {
          v += bias[col];
          Cb[idx] = f2bf(v > 0.f ? v : 0.f);
        } else {
          Cf[idx] = v + bias[col] + bf2f(resb[idx]);
        }
      }
    }
  }
}

// ---------------- flash attention: QBLK=64, KVBLK=64, 4 waves ----------------
// qkv layout: [token][3*1024], col = c3*1024 + h*64 + d
// LDS swizzles:
//   Q/K [64 rows][64 cols] bf16: 16B slot s at (row,colslot c): s = c ^ (row&7)
//     (staged via global_load_lds with pre-swizzled SOURCE column)
//   Vt  [d][kv]: slot s = (kv>>3) ^ ((d>>3)&7)   (write-side conflict-free too)
//   Ps  [16][72] padded rows (144 B = 9*16B, keeps b128 alignment)
__global__ __launch_bounds__(256) void k_attn(
    const unsigned short* __restrict__ qkv,
    unsigned short* __restrict__ outb)   // [token][1024]
{
  __shared__ unsigned short Qs[64 * 64];
  __shared__ unsigned short Ks[64 * 64];
  __shared__ unsigned short Vt[64 * 64];   // transposed+swizzled: Vt[d][kv]
  __shared__ unsigned short Ps[4][16 * 72];

  const int t = threadIdx.x, lane = t & 63, w = t >> 6;
  const int bh = blockIdx.y;
  const int b = bh >> 4, h = bh & 15;
  const int q0 = blockIdx.x * 64;
  const size_t tokbase = (size_t)b * SEQ;
  const int qoff = h * 64, koff = 1024 + h * 64, voff = 2048 + h * 64;
  const int lr = lane & 15, lh = lane >> 4;

  // pre-swizzled staging source: lane covers (row = base + (lane>>3), colslot = (lane&7)^(lane>>3))
  const int srow = lane >> 3;
  const int scol = (((lane & 7) ^ srow) & 7) << 3;

  // stage Q once (rows q0 + w*16 .. +15)
  gload_lds16(qkv + (tokbase + q0 + w * 16 + srow) * 3072 + qoff + scol, &Qs[w * 1024]);
  gload_lds16(qkv + (tokbase + q0 + w * 16 + 8 + srow) * 3072 + qoff + scol, &Qs[w * 1024 + 512]);

  // hoisted LDS read addresses (loop-invariant)
  // Q fragment: row = w*16+lr, colslot lh (aq0) / lh+4 (aq1), swizzled by row&7 = lr&7
  const int qrow = w * 16 + lr;
  const unsigned short* aq0p = &Qs[qrow * 64 + (((lh ^ (lr & 7)) & 7) << 3)];
  const unsigned short* aq1p = &Qs[qrow * 64 + ((((lh + 4) ^ (lr & 7)) & 7) << 3)];
  // K fragment rows nf*16+lr
  const unsigned short* bk0p[4];
  const unsigned short* bk1p[4];
  for (int nf = 0; nf < 4; ++nf) {
    const int krow = nf * 16 + lr;
    bk0p[nf] = &Ks[krow * 64 + (((lh ^ (lr & 7)) & 7) << 3)];
    bk1p[nf] = &Ks[krow * 64 + ((((lh + 4) ^ (lr & 7)) & 7) << 3)];
  }
  // V fragment: row d = nf*16+lr, kv slot lh (vb0) / lh+4 (vb1), swizzle key (d>>3)&7
  const unsigned short* vb0p[4];
  const unsigned short* vb1p[4];
  for (int nf = 0; nf < 4; ++nf) {
    const int d = nf * 16 + lr;
    const int key = (nf * 2 + (lr >> 3)) & 7;
    vb0p[nf] = &Vt[d * 64 + (((lh ^ key) & 7) << 3)];
    vb1p[nf] = &Vt[d * 64 + ((((lh + 4) ^ key) & 7) << 3)];
  }
  // P strip pointers
  const unsigned short* pa0p = &Ps[w][lr * 72 + lh * 8];
  const unsigned short* pa1p = &Ps[w][lr * 72 + 32 + lh * 8];

  // V transpose-staging constants: thread t handles kv row kvr = t>>2, d = d0..d0+15
  const int kvr = t >> 2;
  const int d0 = (t & 3) * 16;
  const int vslotbase = (t & 3) * 2;        // (d>>3)&7 for i<8; +1 for i>=8
  const int kvslot = kvr >> 3;
  const int kvlow = kvr & 7;

  float m_run[4], l_run[4];
  for (int r = 0; r < 4; ++r) { m_run[r] = -1e30f; l_run[r] = 0.f; }
  f32x4 oacc[4] = {};
  const float SCL = 0.125f * 1.44269504089f;  // head_scale * log2(e)

  for (int kt = 0; kt < SEQ / 64; ++kt) {
    __syncthreads();   // prior iter reads done (also Q-load drain at kt=0)
    // stage K (swizzled source)
    gload_lds16(qkv + (tokbase + kt * 64 + w * 16 + srow) * 3072 + koff + scol, &Ks[w * 1024]);
    gload_lds16(qkv + (tokbase + kt * 64 + w * 16 + 8 + srow) * 3072 + koff + scol, &Ks[w * 1024 + 512]);
    // stage V transposed+swizzled (vector global read, scalar LDS writes, conflict-free)
    {
      const unsigned short* vsrc = qkv + (tokbase + kt * 64 + kvr) * 3072 + voff + d0;
      ushort8 v0 = *(const ushort8*)vsrc;
      ushort8 v1 = *(const ushort8*)(vsrc + 8);
      const int s0 = ((kvslot ^ vslotbase) & 7) << 3;
      const int s1 = ((kvslot ^ (vslotbase + 1)) & 7) << 3;
      for (int i = 0; i < 8; ++i) Vt[(d0 + i) * 64 + s0 + kvlow] = v0[i];
      for (int i = 0; i < 8; ++i) Vt[(d0 + 8 + i) * 64 + s1 + kvlow] = v1[i];
    }
    __syncthreads();

    // S = Q @ K^T  (wave w owns q-rows w*16..w*16+15)
    short8 aq0 = *(const short8*)aq0p;
    short8 aq1 = *(const short8*)aq1p;
    f32x4 sacc[4] = {};
    for (int nf = 0; nf < 4; ++nf) {
      short8 bk0 = *(const short8*)bk0p[nf];
      short8 bk1 = *(const short8*)bk1p[nf];
      sacc[nf] = __builtin_amdgcn_mfma_f32_16x16x32_bf16(aq0, bk0, sacc[nf], 0, 0, 0);
      sacc[nf] = __builtin_amdgcn_mfma_f32_16x16x32_bf16(aq1, bk1, sacc[nf], 0, 0, 0);
    }

    // online softmax per q-row (rows lh*4+r, replicated across the 16 lr lanes)
    float p[4][4];
    for (int r = 0; r < 4; ++r) {
      float mx = fmaxf(fmaxf(sacc[0][r], sacc[1][r]), fmaxf(sacc[2][r], sacc[3][r])) * SCL;
      for (int off = 1; off < 16; off <<= 1) mx = fmaxf(mx, __shfl_xor(mx, off));
      if (mx > m_run[r]) {               // defer rescale when max unchanged
        float alpha = exp2f(m_run[r] - mx);
        m_run[r] = mx;
        l_run[r] *= alpha;
        for (int nf = 0; nf < 4; ++nf) oacc[nf][r] *= alpha;
      }
      const float mnew = m_run[r];
      float rs = 0.f;
      for (int nf = 0; nf < 4; ++nf) {
        float pv = exp2f(sacc[nf][r] * SCL - mnew);
        p[nf][r] = pv;
        rs += pv;
      }
      for (int off = 1; off < 16; off <<= 1) rs += __shfl_xor(rs, off);
      l_run[r] += rs;
    }

    // P -> LDS strip (per-wave private, padded rows), then PV
    for (int nf = 0; nf < 4; ++nf)
      for (int r = 0; r < 4; ++r)
        Ps[w][(lh * 4 + r) * 72 + nf * 16 + lr] = f2bf(p[nf][r]);

    short8 pa0 = *(const short8*)pa0p;
    short8 pa1 = *(const short8*)pa1p;
    for (int nf = 0; nf < 4; ++nf) {
      short8 vb0 = *(const short8*)vb0p[nf];
      short8 vb1 = *(const short8*)vb1p[nf];
      oacc[nf] = __builtin_amdgcn_mfma_f32_16x16x32_bf16(pa0, vb0, oacc[nf], 0, 0, 0);
      oacc[nf] = __builtin_amdgcn_mfma_f32_16x16x32_bf16(pa1, vb1, oacc[nf], 0, 0, 0);
    }
  }

  // epilogue: O / l
  for (int nf = 0; nf < 4; ++nf)
    for (int r = 0; r < 4; ++r) {
      const int row = q0 + w * 16 + lh * 4 + r;
      const int col = h * 64 + nf * 16 + lr;
      outb[(tokbase + row) * (size_t)CMODEL + col] = f2bf(oacc[nf][r] / l_run[r]);
    }
}

// ---------------- LayerNorm over rows of 1024 ----------------
template<int OUT_BF>
__global__ __launch_bounds__(256) void k_ln(const float* __restrict__ in,
    const float* __restrict__ g, const float* __restrict__ b,
    float* __restrict__ outf, unsigned short* __restrict__ outb)
{
  const int row = blockIdx.x;
  const int t = threadIdx.x;
  const float4* x4 = (const float4*)(in + (size_t)row * CMODEL);
  float4 v = x4[t];
  float s  = v.x + v.y + v.z + v.w;
  float s2 = v.x * v.x + v.y * v.y + v.z * v.z + v.w * v.w;
  for (int off = 32; off; off >>= 1) { s += __shfl_down(s, off); s2 += __shfl_down(s2, off); }
  __shared__ float red[8];
  __shared__ float stats[2];
  const int wv = t >> 6;
  if ((t & 63) == 0) { red[wv] = s; red[4 + wv] = s2; }
  __syncthreads();
  if (t == 0) {
    float ts  = red[0] + red[1] + red[2] + red[3];
    float ts2 = red[4] + red[5] + red[6] + red[7];
    float mu  = ts * (1.f / CMODEL);
    float var = ts2 * (1.f / CMODEL) - mu * mu;
    stats[0] = mu; stats[1] = rsqrtf(var + 1e-5f);
  }
  __syncthreads();
  const float mu = stats[0], rstd = stats[1];
  float4 gv = ((const float4*)g)[t];
  float4 bv = ((const float4*)b)[t];
  float o0 = (v.x - mu) * rstd * gv.x + bv.x;
  float o1 = (v.y - mu) * rstd * gv.y + bv.y;
  float o2 = (v.z - mu) * rstd * gv.z + bv.z;
  float o3 = (v.w - mu) * rstd * gv.w + bv.w;
  if (OUT_BF) {
    ushort4v o; o[0] = f2bf(o0); o[1] = f2bf(o1); o[2] = f2bf(o2); o[3] = f2bf(o3);
    ((ushort4v*)(outb + (size_t)row * CMODEL))[t] = o;
  } else {
    float4 o; o.x = o0; o.y = o1; o.z = o2; o.w = o3;
    ((float4*)(outf + (size_t)row * CMODEL))[t] = o;
  }
}

// ---------------- launch ----------------
extern "C" void kernel_launch(void* const* d_in, const int* in_sizes, int n_in,
                              void* d_out, int out_size, void* d_ws, size_t ws_size,
                              hipStream_t stream) {
  const float* src    = (const float*)d_in[0];
  const float* w_qkv  = (const float*)d_in[1];
  const float* w_proj = (const float*)d_in[2];
  const float* b_proj = (const float*)d_in[3];
  const float* w1     = (const float*)d_in[4];
  const float* b1     = (const float*)d_in[5];
  const float* w2     = (const float*)d_in[6];
  const float* b2     = (const float*)d_in[7];
  const float* g1     = (const float*)d_in[8];
  const float* be1    = (const float*)d_in[9];
  const float* g2     = (const float*)d_in[10];
  const float* be2    = (const float*)d_in[11];
  float* out = (float*)d_out;

  char* ws = (char*)d_ws;
  size_t off = 0;
  auto alloc = [&](size_t bytes) -> void* {
    void* p = ws + off;
    off += (bytes + 255) & ~(size_t)255;
    return p;
  };
  unsigned short* src_bf   = (unsigned short*)alloc((size_t)TOKENS * CMODEL * 2);
  unsigned short* wqkv_bf  = (unsigned short*)alloc((size_t)3 * CMODEL * CMODEL * 2);
  unsigned short* wproj_bf = (unsigned short*)alloc((size_t)CMODEL * CMODEL * 2);
  unsigned short* w1_bf    = (unsigned short*)alloc((size_t)DFF * CMODEL * 2);
  unsigned short* w2_bf    = (unsigned short*)alloc((size_t)CMODEL * DFF * 2);
  unsigned short* qkv_bf   = (unsigned short*)alloc((size_t)TOKENS * 3 * CMODEL * 2);
  unsigned short* attno_bf = (unsigned short*)alloc((size_t)TOKENS * CMODEL * 2);
  float*          z_f32    = (float*)alloc((size_t)TOKENS * CMODEL * 4);
  unsigned short* x_bf     = (unsigned short*)alloc((size_t)TOKENS * CMODEL * 2);
  unsigned short* h_bf     = (unsigned short*)alloc((size_t)TOKENS * DFF * 2);

  auto cvt = [&](const float* i, unsigned short* o, size_t n) {
    int n8 = (int)(n / 8);
    k_cvt<<<(n8 + 255) / 256, 256, 0, stream>>>(i, o, n8);
  };
  cvt(src,    src_bf,   (size_t)TOKENS * CMODEL);
  cvt(w_qkv,  wqkv_bf,  (size_t)3 * CMODEL * CMODEL);
  cvt(w_proj, wproj_bf, (size_t)CMODEL * CMODEL);
  cvt(w1,     w1_bf,    (size_t)DFF * CMODEL);
  cvt(w2,     w2_bf,    (size_t)CMODEL * DFF);

  // qkv = src @ w_qkv^T            [4096, 3072]
  k_gemm_bt<0><<<dim3(3072 / 128, TOKENS / 128), 256, 0, stream>>>(
      src_bf, wqkv_bf, qkv_bf, nullptr, nullptr, nullptr, nullptr, TOKENS, 3 * CMODEL, CMODEL);
  // attention -> attno             [4096, 1024]
  k_attn<<<dim3(SEQ / 64, 2 * HEADS), 256, 0, stream>>>(qkv_bf, attno_bf);
  // z = attno @ w_proj^T + b_proj + src   (f32)
  k_gemm_bt<1><<<dim3(CMODEL / 128, TOKENS / 128), 256, 0, stream>>>(
      attno_bf, wproj_bf, nullptr, z_f32, b_proj, src, nullptr, TOKENS, CMODEL, CMODEL);
  // x = LN1(z) -> bf16
  k_ln<1><<<TOKENS, 256, 0, stream>>>(z_f32, g1, be1, nullptr, x_bf);
  // h = relu(x @ w1^T + b1) -> bf16       [4096, 4096]
  k_gemm_bt<2><<<dim3(DFF / 128, TOKENS / 128), 256, 0, stream>>>(
      x_bf, w1_bf, h_bf, nullptr, b1, nullptr, nullptr, TOKENS, DFF, CMODEL);
  // z = h @ w2^T + b2 + x  (f32)
  k_gemm_bt<3><<<dim3(CMODEL / 128, TOKENS / 128), 256, 0, stream>>>(
      h_bf, w2_bf, nullptr, z_f32, b2, nullptr, x_bf, TOKENS, CMODEL, DFF);
  // out = LN2(z)
  k_ln<0><<<TOKENS, 256, 0, stream>>>(z_f32, g2, be2, out, nullptr);
}

// Round 3
// 445.434 us; speedup vs baseline: 1.1919x; 1.1680x over previous
//
#include <hip/hip_runtime.h>
#include <hip/hip_bf16.h>
#include <stdint.h>

// ---- problem constants ----
#define TOKENS 4096      // B*N = 2*2048
#define SEQ    2048
#define CMODEL 1024
#define HEADS  16
#define HDIM   64
#define DFF    4096
#define NT     (SEQ / 64)

typedef __attribute__((ext_vector_type(8))) short     short8;
typedef __attribute__((ext_vector_type(8))) unsigned short ushort8;
typedef __attribute__((ext_vector_type(4))) unsigned short ushort4v;
typedef __attribute__((ext_vector_type(4))) float     f32x4;

typedef const __attribute__((address_space(1))) void gbl_cvoid;
typedef __attribute__((address_space(3))) void lds_void;

__device__ inline unsigned short f2bf(float f) {
  unsigned int u = __builtin_bit_cast(unsigned int, f);
  u += 0x7fffu + ((u >> 16) & 1u);
  return (unsigned short)(u >> 16);
}
__device__ inline float bf2f(unsigned short h) {
  unsigned int u = ((unsigned int)h) << 16;
  return __builtin_bit_cast(float, u);
}

__device__ inline void gload_lds16(const unsigned short* g, unsigned short* lds) {
  __builtin_amdgcn_global_load_lds((gbl_cvoid*)g, (lds_void*)lds, 16, 0, 0);
}

// ---------------- f32 -> bf16 convert (8 elems/thread) ----------------
__global__ __launch_bounds__(256) void k_cvt(const float* __restrict__ in,
                                             unsigned short* __restrict__ out, int n8) {
  int i = blockIdx.x * 256 + threadIdx.x;
  if (i >= n8) return;
  const float4* p = (const float4*)in + 2 * (size_t)i;
  float4 a = p[0], b = p[1];
  ushort8 o;
  o[0] = f2bf(a.x); o[1] = f2bf(a.y); o[2] = f2bf(a.z); o[3] = f2bf(a.w);
  o[4] = f2bf(b.x); o[5] = f2bf(b.y); o[6] = f2bf(b.z); o[7] = f2bf(b.w);
  ((ushort8*)out)[i] = o;
}

// ---------------- bf16 BT-GEMM: C[M,N] = A[M,K] @ B[N,K]^T ----------------
// 128x128 tile, BK=32, 4 waves (2x2). Double-buffered LDS, counted vmcnt(4)
// prefetch pipeline (T3-min): STAGE(kt+1) issued before compute(kt); loads
// stay in flight across the raw barrier (never drained to 0 mid-loop).
template<int EPI>
__global__ __launch_bounds__(256) void k_gemm_bt(
    const unsigned short* __restrict__ A,   // [M,K] bf16
    const unsigned short* __restrict__ B,   // [N,K] bf16 (BT)
    unsigned short* __restrict__ Cb,
    float* __restrict__ Cf,
    const float* __restrict__ bias,
    const float* __restrict__ resf,
    const unsigned short* __restrict__ resb,
    int M, int N, int K)
{
  __shared__ unsigned short As[2][128 * 32];
  __shared__ unsigned short Bs[2][128 * 32];
  const int t = threadIdx.x;
  const int lane = t & 63;
  const int w = t >> 6;
  const int wr = w >> 1, wc = w & 1;
  const int m0 = blockIdx.y * 128, n0 = blockIdx.x * 128;

  const int e0 = w * 1024 + lane * 8;
  const int e1 = e0 + 512;
  const int r0 = e0 >> 5, c0 = e0 & 31;
  const int r1 = e1 >> 5, c1 = e1 & 31;

  f32x4 acc[4][4] = {};
  const int lr = lane & 15, lh = lane >> 4;
  const int nkt = K >> 5;

  // prologue: stage tile 0 into buffer 0
  gload_lds16(A + (size_t)(m0 + r0) * K + c0, &As[0][w * 1024]);
  gload_lds16(A + (size_t)(m0 + r1) * K + c1, &As[0][w * 1024 + 512]);
  gload_lds16(B + (size_t)(n0 + r0) * K + c0, &Bs[0][w * 1024]);
  gload_lds16(B + (size_t)(n0 + r1) * K + c1, &Bs[0][w * 1024 + 512]);

  for (int kt = 0; kt < nkt; ++kt) {
    const int cur = kt & 1;
    if (kt + 1 < nkt) {
      const int kb = (kt + 1) << 5;
      gload_lds16(A + (size_t)(m0 + r0) * K + kb + c0, &As[cur ^ 1][w * 1024]);
      gload_lds16(A + (size_t)(m0 + r1) * K + kb + c1, &As[cur ^ 1][w * 1024 + 512]);
      gload_lds16(B + (size_t)(n0 + r0) * K + kb + c0, &Bs[cur ^ 1][w * 1024]);
      gload_lds16(B + (size_t)(n0 + r1) * K + kb + c1, &Bs[cur ^ 1][w * 1024 + 512]);
      asm volatile("s_waitcnt vmcnt(4)" ::: "memory");   // tile kt landed; kt+1 in flight
    } else {
      asm volatile("s_waitcnt vmcnt(0)" ::: "memory");
    }
    __builtin_amdgcn_s_barrier();
    __builtin_amdgcn_sched_barrier(0);
    short8 af[4], bg[4];
    for (int m = 0; m < 4; ++m)
      af[m] = *(const short8*)&As[cur][(wr * 64 + m * 16 + lr) * 32 + lh * 8];
    for (int n = 0; n < 4; ++n)
      bg[n] = *(const short8*)&Bs[cur][(wc * 64 + n * 16 + lr) * 32 + lh * 8];
    for (int m = 0; m < 4; ++m)
      for (int n = 0; n < 4; ++n)
        acc[m][n] = __builtin_amdgcn_mfma_f32_16x16x32_bf16(af[m], bg[n], acc[m][n], 0, 0, 0);
    __builtin_amdgcn_s_barrier();   // readers done before next-iter DMA overwrites buf[cur]
    __builtin_amdgcn_sched_barrier(0);
  }

  for (int m = 0; m < 4; ++m) {
    for (int n = 0; n < 4; ++n) {
      const int col = n0 + wc * 64 + n * 16 + lr;
      for (int r = 0; r < 4; ++r) {
        const int row = m0 + wr * 64 + m * 16 + lh * 4 + r;
        const size_t idx = (size_t)row * N + col;
        float v = acc[m][n][r];
        if (EPI == 0) {
          Cb[idx] = f2bf(v);
        } else if (EPI == 1) {
          Cf[idx] = v + bias[col] + resf[idx];
        } else if (EPI == 2) {
          v += bias[col];
          Cb[idx] = f2bf(v > 0.f ? v : 0.f);
        } else {
          Cf[idx] = v + bias[col] + bf2f(resb[idx]);
        }
      }
    }
  }
}

// ---------------- flash attention: QBLK=64, KVBLK=64, 4 waves ----------------
// Swapped QK^T (mfma(K,Q) -> S[kv][q], kv reduction lane-local), double-buffered
// K (LDS DMA) and V (reg-staged, async-split), counted vmcnt(4), setprio on MFMA.
__global__ __launch_bounds__(256) void k_attn(
    const unsigned short* __restrict__ qkv,
    unsigned short* __restrict__ outb)   // [token][1024]
{
  __shared__ unsigned short Qs[64 * 64];
  __shared__ unsigned short Ks[2][64 * 64];
  __shared__ unsigned short Vt[2][64 * 64];   // transposed+swizzled Vt[d][kv]
  __shared__ unsigned short Ps[4][16 * 72];

  const int t = threadIdx.x, lane = t & 63, w = t >> 6;
  const int bh = blockIdx.y;
  const int b = bh >> 4, h = bh & 15;
  const int q0 = blockIdx.x * 64;
  const size_t tokbase = (size_t)b * SEQ;
  const int qoff = h * 64, koff = 1024 + h * 64, voff = 2048 + h * 64;
  const int lr = lane & 15, lh = lane >> 4, lh4 = lh * 4;

  // pre-swizzled staging source (rule #21: linear LDS dest + inv-swizzled src)
  const int srow = lane >> 3;
  const int scol = (((lane & 7) ^ srow) & 7) << 3;

  // prologue: stage Q, K tile0 (DMA), V tile0 (regs)
  gload_lds16(qkv + (tokbase + q0 + w * 16 + srow) * 3072 + qoff + scol, &Qs[w * 1024]);
  gload_lds16(qkv + (tokbase + q0 + w * 16 + 8 + srow) * 3072 + qoff + scol, &Qs[w * 1024 + 512]);
  gload_lds16(qkv + (tokbase + w * 16 + srow) * 3072 + koff + scol, &Ks[0][w * 1024]);
  gload_lds16(qkv + (tokbase + w * 16 + 8 + srow) * 3072 + koff + scol, &Ks[0][w * 1024 + 512]);

  const int kvr = t >> 2, d0v = (t & 3) * 16;
  const int vslotbase = (t & 3) * 2, kvslot = kvr >> 3, kvlow = kvr & 7;
  const int s0v = ((kvslot ^ vslotbase) & 7) << 3;
  const int s1v = ((kvslot ^ (vslotbase + 1)) & 7) << 3;

  ushort8 vA0, vA1, vB0, vB1;
  {
    const unsigned short* vsrc = qkv + (tokbase + kvr) * 3072 + voff + d0v;
    vA0 = *(const ushort8*)vsrc;
    vA1 = *(const ushort8*)(vsrc + 8);
  }
  asm volatile("s_waitcnt vmcnt(0)" ::: "memory");
  __builtin_amdgcn_s_barrier();
  __builtin_amdgcn_sched_barrier(0);

  // Q fragments (B-operand of swapped QK^T), hoisted out of the loop
  const int qrow = w * 16 + lr;
  const short8 aq0 = *(const short8*)&Qs[qrow * 64 + (((lh ^ (lr & 7)) & 7) << 3)];
  const short8 aq1 = *(const short8*)&Qs[qrow * 64 + ((((lh + 4) ^ (lr & 7)) & 7) << 3)];

  int koffs0[4], koffs1[4], voffs0[4], voffs1[4];
  for (int nf = 0; nf < 4; ++nf) {
    const int krow = nf * 16 + lr;
    koffs0[nf] = krow * 64 + (((lh ^ (lr & 7)) & 7) << 3);
    koffs1[nf] = krow * 64 + ((((lh + 4) ^ (lr & 7)) & 7) << 3);
    const int d = nf * 16 + lr;
    const int key = (nf * 2 + (lr >> 3)) & 7;
    voffs0[nf] = d * 64 + (((lh ^ key) & 7) << 3);
    voffs1[nf] = d * 64 + ((((lh + 4) ^ key) & 7) << 3);
  }
  const unsigned short* pa0p = &Ps[w][lr * 72 + lh * 8];
  const unsigned short* pa1p = &Ps[w][lr * 72 + 32 + lh * 8];

  float m_run = -1e30f, l_run = 0.f;
  f32x4 oacc[4] = {};
  const float SCL = 0.125f * 1.44269504089f;  // head_scale * log2(e)

#define ATTN_STEP(CUR, VA0_, VA1_, VN0_, VN1_, KT)                                \
  {                                                                               \
    const int ktn = (KT) + 1;                                                     \
    if (ktn < NT) {                                                               \
      gload_lds16(qkv + (tokbase + ktn * 64 + w * 16 + srow) * 3072 + koff + scol,\
                  &Ks[1 - (CUR)][w * 1024]);                                      \
      gload_lds16(qkv + (tokbase + ktn * 64 + w * 16 + 8 + srow) * 3072 + koff + scol,\
                  &Ks[1 - (CUR)][w * 1024 + 512]);                                \
      const unsigned short* vsrc = qkv + (tokbase + ktn * 64 + kvr) * 3072 + voff + d0v;\
      VN0_ = *(const ushort8*)vsrc;                                               \
      VN1_ = *(const ushort8*)(vsrc + 8);                                         \
      asm volatile("s_waitcnt vmcnt(4)" ::: "memory");                            \
    } else {                                                                      \
      asm volatile("s_waitcnt vmcnt(0)" ::: "memory");                            \
    }                                                                             \
    __builtin_amdgcn_s_barrier();                                                 \
    __builtin_amdgcn_sched_barrier(0);                                            \
    /* write V tile (loaded last iter) into Vt[CUR]; overlaps QK+softmax */       \
    for (int i = 0; i < 8; ++i) Vt[CUR][(d0v + i) * 64 + s0v + kvlow] = VA0_[i];  \
    for (int i = 0; i < 8; ++i) Vt[CUR][(d0v + 8 + i) * 64 + s1v + kvlow] = VA1_[i];\
    f32x4 sacc[4] = {};                                                           \
    __builtin_amdgcn_s_setprio(1);                                                \
    for (int nf = 0; nf < 4; ++nf) {                                              \
      short8 bk0 = *(const short8*)&Ks[CUR][koffs0[nf]];                          \
      short8 bk1 = *(const short8*)&Ks[CUR][koffs1[nf]];                          \
      sacc[nf] = __builtin_amdgcn_mfma_f32_16x16x32_bf16(bk0, aq0, sacc[nf], 0, 0, 0);\
      sacc[nf] = __builtin_amdgcn_mfma_f32_16x16x32_bf16(bk1, aq1, sacc[nf], 0, 0, 0);\
    }                                                                             \
    __builtin_amdgcn_s_setprio(0);                                                \
    /* lane-local softmax for q=lr: 16 in-reg values + 2 shfl */                  \
    float tm = fmaxf(fmaxf(fmaxf(sacc[0][0], sacc[0][1]), fmaxf(sacc[0][2], sacc[0][3])),\
                     fmaxf(fmaxf(sacc[1][0], sacc[1][1]), fmaxf(sacc[1][2], sacc[1][3])));\
    tm = fmaxf(tm, fmaxf(fmaxf(fmaxf(sacc[2][0], sacc[2][1]), fmaxf(sacc[2][2], sacc[2][3])),\
                         fmaxf(fmaxf(sacc[3][0], sacc[3][1]), fmaxf(sacc[3][2], sacc[3][3]))));\
    tm *= SCL;                                                                    \
    tm = fmaxf(tm, __shfl_xor(tm, 16));                                           \
    tm = fmaxf(tm, __shfl_xor(tm, 32));                                           \
    if (__any(tm > m_run)) {                                                      \
      const float mnew = fmaxf(m_run, tm);                                        \
      const float alpha = exp2f(m_run - mnew);                                    \
      m_run = mnew; l_run *= alpha;                                               \
      const float ar0 = __shfl(alpha, lh4 + 0), ar1 = __shfl(alpha, lh4 + 1);     \
      const float ar2 = __shfl(alpha, lh4 + 2), ar3 = __shfl(alpha, lh4 + 3);     \
      for (int nf = 0; nf < 4; ++nf) {                                            \
        oacc[nf][0] *= ar0; oacc[nf][1] *= ar1;                                   \
        oacc[nf][2] *= ar2; oacc[nf][3] *= ar3;                                   \
      }                                                                           \
    }                                                                             \
    float rs = 0.f;                                                               \
    for (int nf = 0; nf < 4; ++nf) {                                              \
      float p0 = exp2f(__builtin_fmaf(sacc[nf][0], SCL, -m_run));                 \
      float p1 = exp2f(__builtin_fmaf(sacc[nf][1], SCL, -m_run));                 \
      float p2 = exp2f(__builtin_fmaf(sacc[nf][2], SCL, -m_run));                 \
      float p3 = exp2f(__builtin_fmaf(sacc[nf][3], SCL, -m_run));                 \
      rs += (p0 + p1) + (p2 + p3);                                                \
      uint2 pw;                                                                   \
      pw.x = (unsigned)f2bf(p0) | ((unsigned)f2bf(p1) << 16);                     \
      pw.y = (unsigned)f2bf(p2) | ((unsigned)f2bf(p3) << 16);                     \
      *(uint2*)&Ps[w][lr * 72 + nf * 16 + lh4] = pw;                              \
    }                                                                             \
    rs += __shfl_xor(rs, 16);                                                     \
    rs += __shfl_xor(rs, 32);                                                     \
    l_run += rs;                                                                  \
    short8 pa0 = *(const short8*)pa0p;                                            \
    short8 pa1 = *(const short8*)pa1p;                                            \
    asm volatile("s_waitcnt lgkmcnt(0)" ::: "memory");                            \
    __builtin_amdgcn_s_barrier();                                                 \
    __builtin_amdgcn_sched_barrier(0);                                            \
    __builtin_amdgcn_s_setprio(1);                                                \
    for (int nf = 0; nf < 4; ++nf) {                                              \
      short8 vb0 = *(const short8*)&Vt[CUR][voffs0[nf]];                          \
      short8 vb1 = *(const short8*)&Vt[CUR][voffs1[nf]];                          \
      oacc[nf] = __builtin_amdgcn_mfma_f32_16x16x32_bf16(pa0, vb0, oacc[nf], 0, 0, 0);\
      oacc[nf] = __builtin_amdgcn_mfma_f32_16x16x32_bf16(pa1, vb1, oacc[nf], 0, 0, 0);\
    }                                                                             \
    __builtin_amdgcn_s_setprio(0);                                                \
  }

  for (int kt2 = 0; kt2 < NT; kt2 += 2) {
    ATTN_STEP(0, vA0, vA1, vB0, vB1, kt2)
    ATTN_STEP(1, vB0, vB1, vA0, vA1, kt2 + 1)
  }
#undef ATTN_STEP

  // epilogue: O / l   (l for q'=lh4+r lives in lane lh4+r)
  const float lf0 = __shfl(l_run, lh4 + 0);
  const float lf1 = __shfl(l_run, lh4 + 1);
  const float lf2 = __shfl(l_run, lh4 + 2);
  const float lf3 = __shfl(l_run, lh4 + 3);
  const float ri0 = 1.f / lf0, ri1 = 1.f / lf1, ri2 = 1.f / lf2, ri3 = 1.f / lf3;
  for (int nf = 0; nf < 4; ++nf) {
    const int col = h * 64 + nf * 16 + lr;
    const size_t rowb = (tokbase + q0 + w * 16 + lh4) * (size_t)CMODEL + col;
    outb[rowb]               = f2bf(oacc[nf][0] * ri0);
    outb[rowb + CMODEL]      = f2bf(oacc[nf][1] * ri1);
    outb[rowb + 2 * CMODEL]  = f2bf(oacc[nf][2] * ri2);
    outb[rowb + 3 * CMODEL]  = f2bf(oacc[nf][3] * ri3);
  }
}

// ---------------- LayerNorm over rows of 1024 ----------------
template<int OUT_BF>
__global__ __launch_bounds__(256) void k_ln(const float* __restrict__ in,
    const float* __restrict__ g, const float* __restrict__ b,
    float* __restrict__ outf, unsigned short* __restrict__ outb)
{
  const int row = blockIdx.x;
  const int t = threadIdx.x;
  const float4* x4 = (const float4*)(in + (size_t)row * CMODEL);
  float4 v = x4[t];
  float s  = v.x + v.y + v.z + v.w;
  float s2 = v.x * v.x + v.y * v.y + v.z * v.z + v.w * v.w;
  for (int off = 32; off; off >>= 1) { s += __shfl_down(s, off); s2 += __shfl_down(s2, off); }
  __shared__ float red[8];
  __shared__ float stats[2];
  const int wv = t >> 6;
  if ((t & 63) == 0) { red[wv] = s; red[4 + wv] = s2; }
  __syncthreads();
  if (t == 0) {
    float ts  = red[0] + red[1] + red[2] + red[3];
    float ts2 = red[4] + red[5] + red[6] + red[7];
    float mu  = ts * (1.f / CMODEL);
    float var = ts2 * (1.f / CMODEL) - mu * mu;
    stats[0] = mu; stats[1] = rsqrtf(var + 1e-5f);
  }
  __syncthreads();
  const float mu = stats[0], rstd = stats[1];
  float4 gv = ((const float4*)g)[t];
  float4 bv = ((const float4*)b)[t];
  float o0 = (v.x - mu) * rstd * gv.x + bv.x;
  float o1 = (v.y - mu) * rstd * gv.y + bv.y;
  float o2 = (v.z - mu) * rstd * gv.z + bv.z;
  float o3 = (v.w - mu) * rstd * gv.w + bv.w;
  if (OUT_BF) {
    ushort4v o; o[0] = f2bf(o0); o[1] = f2bf(o1); o[2] = f2bf(o2); o[3] = f2bf(o3);
    ((ushort4v*)(outb + (size_t)row * CMODEL))[t] = o;
  } else {
    float4 o; o.x = o0; o.y = o1; o.z = o2; o.w = o3;
    ((float4*)(outf + (size_t)row * CMODEL))[t] = o;
  }
}

// ---------------- launch ----------------
extern "C" void kernel_launch(void* const* d_in, const int* in_sizes, int n_in,
                              void* d_out, int out_size, void* d_ws, size_t ws_size,
                              hipStream_t stream) {
  const float* src    = (const float*)d_in[0];
  const float* w_qkv  = (const float*)d_in[1];
  const float* w_proj = (const float*)d_in[2];
  const float* b_proj = (const float*)d_in[3];
  const float* w1     = (const float*)d_in[4];
  const float* b1     = (const float*)d_in[5];
  const float* w2     = (const float*)d_in[6];
  const float* b2     = (const float*)d_in[7];
  const float* g1     = (const float*)d_in[8];
  const float* be1    = (const float*)d_in[9];
  const float* g2     = (const float*)d_in[10];
  const float* be2    = (const float*)d_in[11];
  float* out = (float*)d_out;

  char* ws = (char*)d_ws;
  size_t off = 0;
  auto alloc = [&](size_t bytes) -> void* {
    void* p = ws + off;
    off += (bytes + 255) & ~(size_t)255;
    return p;
  };
  unsigned short* src_bf   = (unsigned short*)alloc((size_t)TOKENS * CMODEL * 2);
  unsigned short* wqkv_bf  = (unsigned short*)alloc((size_t)3 * CMODEL * CMODEL * 2);
  unsigned short* wproj_bf = (unsigned short*)alloc((size_t)CMODEL * CMODEL * 2);
  unsigned short* w1_bf    = (unsigned short*)alloc((size_t)DFF * CMODEL * 2);
  unsigned short* w2_bf    = (unsigned short*)alloc((size_t)CMODEL * DFF * 2);
  unsigned short* qkv_bf   = (unsigned short*)alloc((size_t)TOKENS * 3 * CMODEL * 2);
  unsigned short* attno_bf = (unsigned short*)alloc((size_t)TOKENS * CMODEL * 2);
  float*          z_f32    = (float*)alloc((size_t)TOKENS * CMODEL * 4);
  unsigned short* x_bf     = (unsigned short*)alloc((size_t)TOKENS * CMODEL * 2);
  unsigned short* h_bf     = (unsigned short*)alloc((size_t)TOKENS * DFF * 2);

  auto cvt = [&](const float* i, unsigned short* o, size_t n) {
    int n8 = (int)(n / 8);
    k_cvt<<<(n8 + 255) / 256, 256, 0, stream>>>(i, o, n8);
  };
  cvt(src,    src_bf,   (size_t)TOKENS * CMODEL);
  cvt(w_qkv,  wqkv_bf,  (size_t)3 * CMODEL * CMODEL);
  cvt(w_proj, wproj_bf, (size_t)CMODEL * CMODEL);
  cvt(w1,     w1_bf,    (size_t)DFF * CMODEL);
  cvt(w2,     w2_bf,    (size_t)CMODEL * DFF);

  // qkv = src @ w_qkv^T            [4096, 3072]
  k_gemm_bt<0><<<dim3(3072 / 128, TOKENS / 128), 256, 0, stream>>>(
      src_bf, wqkv_bf, qkv_bf, nullptr, nullptr, nullptr, nullptr, TOKENS, 3 * CMODEL, CMODEL);
  // attention -> attno             [4096, 1024]
  k_attn<<<dim3(SEQ / 64, 2 * HEADS), 256, 0, stream>>>(qkv_bf, attno_bf);
  // z = attno @ w_proj^T + b_proj + src   (f32)
  k_gemm_bt<1><<<dim3(CMODEL / 128, TOKENS / 128), 256, 0, stream>>>(
      attno_bf, wproj_bf, nullptr, z_f32, b_proj, src, nullptr, TOKENS, CMODEL, CMODEL);
  // x = LN1(z) -> bf16
  k_ln<1><<<TOKENS, 256, 0, stream>>>(z_f32, g1, be1, nullptr, x_bf);
  // h = relu(x @ w1^T + b1) -> bf16       [4096, 4096]
  k_gemm_bt<2><<<dim3(DFF / 128, TOKENS / 128), 256, 0, stream>>>(
      x_bf, w1_bf, h_bf, nullptr, b1, nullptr, nullptr, TOKENS, DFF, CMODEL);
  // z = h @ w2^T + b2 + x  (f32)
  k_gemm_bt<3><<<dim3(CMODEL / 128, TOKENS / 128), 256, 0, stream>>>(
      h_bf, w2_bf, nullptr, z_f32, b2, nullptr, x_bf, TOKENS, CMODEL, DFF);
  // out = LN2(z)
  k_ln<0><<<TOKENS, 256, 0, stream>>>(z_f32, g2, be2, out, nullptr);
}

// Round 4
// 437.109 us; speedup vs baseline: 1.2146x; 1.0190x over previous
//
#include <hip/hip_runtime.h>
#include <hip/hip_bf16.h>
#include <stdint.h>

// ---- problem constants ----
#define TOKENS 4096      // B*N = 2*2048
#define SEQ    2048
#define CMODEL 1024
#define HEADS  16
#define HDIM   64
#define DFF    4096
#define NT     (SEQ / 64)

typedef __attribute__((ext_vector_type(8))) short     short8;
typedef __attribute__((ext_vector_type(8))) unsigned short ushort8;
typedef __attribute__((ext_vector_type(4))) unsigned short ushort4v;
typedef __attribute__((ext_vector_type(4))) float     f32x4;

typedef const __attribute__((address_space(1))) void gbl_cvoid;
typedef __attribute__((address_space(3))) void lds_void;

__device__ inline unsigned short f2bf(float f) {
  unsigned int u = __builtin_bit_cast(unsigned int, f);
  u += 0x7fffu + ((u >> 16) & 1u);
  return (unsigned short)(u >> 16);
}
__device__ inline float bf2f(unsigned short h) {
  unsigned int u = ((unsigned int)h) << 16;
  return __builtin_bit_cast(float, u);
}

__device__ inline void gload_lds16(const unsigned short* g, unsigned short* lds) {
  __builtin_amdgcn_global_load_lds((gbl_cvoid*)g, (lds_void*)lds, 16, 0, 0);
}

// ---------------- f32 -> bf16 convert (8 elems/thread) ----------------
__global__ __launch_bounds__(256) void k_cvt(const float* __restrict__ in,
                                             unsigned short* __restrict__ out, int n8) {
  int i = blockIdx.x * 256 + threadIdx.x;
  if (i >= n8) return;
  const float4* p = (const float4*)in + 2 * (size_t)i;
  float4 a = p[0], b = p[1];
  ushort8 o;
  o[0] = f2bf(a.x); o[1] = f2bf(a.y); o[2] = f2bf(a.z); o[3] = f2bf(a.w);
  o[4] = f2bf(b.x); o[5] = f2bf(b.y); o[6] = f2bf(b.z); o[7] = f2bf(b.w);
  ((ushort8*)out)[i] = o;
}

// ---------------- bf16 BT-GEMM 128x128: C[M,N] = A[M,K] @ B[N,K]^T --------
// BK=32, 4 waves (2x2), dbuf + counted vmcnt(4) pipeline, XCD swizzle.
template<int EPI>
__global__ __launch_bounds__(256) void k_gemm_bt(
    const unsigned short* __restrict__ A,
    const unsigned short* __restrict__ B,
    unsigned short* __restrict__ Cb,
    float* __restrict__ Cf,
    const float* __restrict__ bias,
    const float* __restrict__ resf,
    const unsigned short* __restrict__ resb,
    int M, int N, int K)
{
  __shared__ unsigned short As[2][128 * 32];
  __shared__ unsigned short Bs[2][128 * 32];
  const int t = threadIdx.x;
  const int lane = t & 63;
  const int w = t >> 6;
  const int wr = w >> 1, wc = w & 1;
  // XCD-aware swizzle (nwg % 8 == 0 for all our grids)
  const int nwg = gridDim.x * gridDim.y;
  const int bid = blockIdx.y * gridDim.x + blockIdx.x;
  const int swz = (bid & 7) * (nwg >> 3) + (bid >> 3);
  const int n0 = (swz % gridDim.x) * 128;
  const int m0 = (swz / gridDim.x) * 128;

  const int e0 = w * 1024 + lane * 8;
  const int e1 = e0 + 512;
  const int r0 = e0 >> 5, c0 = e0 & 31;
  const int r1 = e1 >> 5, c1 = e1 & 31;

  f32x4 acc[4][4] = {};
  const int lr = lane & 15, lh = lane >> 4;
  const int nkt = K >> 5;

  gload_lds16(A + (size_t)(m0 + r0) * K + c0, &As[0][w * 1024]);
  gload_lds16(A + (size_t)(m0 + r1) * K + c1, &As[0][w * 1024 + 512]);
  gload_lds16(B + (size_t)(n0 + r0) * K + c0, &Bs[0][w * 1024]);
  gload_lds16(B + (size_t)(n0 + r1) * K + c1, &Bs[0][w * 1024 + 512]);

  for (int kt = 0; kt < nkt; ++kt) {
    const int cur = kt & 1;
    if (kt + 1 < nkt) {
      const int kb = (kt + 1) << 5;
      gload_lds16(A + (size_t)(m0 + r0) * K + kb + c0, &As[cur ^ 1][w * 1024]);
      gload_lds16(A + (size_t)(m0 + r1) * K + kb + c1, &As[cur ^ 1][w * 1024 + 512]);
      gload_lds16(B + (size_t)(n0 + r0) * K + kb + c0, &Bs[cur ^ 1][w * 1024]);
      gload_lds16(B + (size_t)(n0 + r1) * K + kb + c1, &Bs[cur ^ 1][w * 1024 + 512]);
      asm volatile("s_waitcnt vmcnt(4)" ::: "memory");
    } else {
      asm volatile("s_waitcnt vmcnt(0)" ::: "memory");
    }
    __builtin_amdgcn_s_barrier();
    __builtin_amdgcn_sched_barrier(0);
    short8 af[4], bg[4];
#pragma unroll
    for (int m = 0; m < 4; ++m)
      af[m] = *(const short8*)&As[cur][(wr * 64 + m * 16 + lr) * 32 + lh * 8];
#pragma unroll
    for (int n = 0; n < 4; ++n)
      bg[n] = *(const short8*)&Bs[cur][(wc * 64 + n * 16 + lr) * 32 + lh * 8];
#pragma unroll
    for (int m = 0; m < 4; ++m)
#pragma unroll
      for (int n = 0; n < 4; ++n)
        acc[m][n] = __builtin_amdgcn_mfma_f32_16x16x32_bf16(af[m], bg[n], acc[m][n], 0, 0, 0);
    __builtin_amdgcn_s_barrier();
    __builtin_amdgcn_sched_barrier(0);
  }

  for (int m = 0; m < 4; ++m) {
    for (int n = 0; n < 4; ++n) {
      const int col = n0 + wc * 64 + n * 16 + lr;
      for (int r = 0; r < 4; ++r) {
        const int row = m0 + wr * 64 + m * 16 + lh * 4 + r;
        const size_t idx = (size_t)row * N + col;
        float v = acc[m][n][r];
        if (EPI == 0) {
          Cb[idx] = f2bf(v);
        } else if (EPI == 1) {
          Cf[idx] = v + bias[col] + resf[idx];
        } else if (EPI == 2) {
          v += bias[col];
          Cb[idx] = f2bf(v > 0.f ? v : 0.f);
        } else {
          Cf[idx] = v + bias[col] + bf2f(resb[idx]);
        }
      }
    }
  }
}

// ---------------- bf16 BT-GEMM 256x256: 8 waves (2Mx4N), BK=32 -------------
// Per-wave 128x64 output (8x4 frags). LDS rows 64 B -> fragment ds_read_b128
// is a contiguous 1024B wave read (conflict-free by layout, no swizzle).
// Same counted-vmcnt(4) dbuf pipeline as the 128^2 kernel.
template<int EPI>
__global__ __launch_bounds__(512) void k_gemm256(
    const unsigned short* __restrict__ A,
    const unsigned short* __restrict__ B,
    unsigned short* __restrict__ Cb,
    const float* __restrict__ bias,
    int M, int N, int K)
{
  __shared__ unsigned short As[2][256 * 32];
  __shared__ unsigned short Bs[2][256 * 32];
  const int t = threadIdx.x;
  const int lane = t & 63;
  const int w = t >> 6;
  const int wr = w >> 2, wc = w & 3;
  const int nwg = gridDim.x * gridDim.y;
  const int bid = blockIdx.y * gridDim.x + blockIdx.x;
  const int swz = (bid & 7) * (nwg >> 3) + (bid >> 3);
  const int n0 = (swz % gridDim.x) * 256;
  const int m0 = (swz / gridDim.x) * 256;

  // staging: wave w covers elems [w*1024, w*1024+1024) of the 256x32 tile
  const int e0 = w * 1024 + lane * 8;
  const int e1 = e0 + 512;
  const int r0 = e0 >> 5, c0 = e0 & 31;
  const int r1 = e1 >> 5, c1 = e1 & 31;

  f32x4 acc[8][4] = {};
  const int lr = lane & 15, lh = lane >> 4;
  const int nkt = K >> 5;

  gload_lds16(A + (size_t)(m0 + r0) * K + c0, &As[0][w * 1024]);
  gload_lds16(A + (size_t)(m0 + r1) * K + c1, &As[0][w * 1024 + 512]);
  gload_lds16(B + (size_t)(n0 + r0) * K + c0, &Bs[0][w * 1024]);
  gload_lds16(B + (size_t)(n0 + r1) * K + c1, &Bs[0][w * 1024 + 512]);

  for (int kt = 0; kt < nkt; ++kt) {
    const int cur = kt & 1;
    if (kt + 1 < nkt) {
      const int kb = (kt + 1) << 5;
      gload_lds16(A + (size_t)(m0 + r0) * K + kb + c0, &As[cur ^ 1][w * 1024]);
      gload_lds16(A + (size_t)(m0 + r1) * K + kb + c1, &As[cur ^ 1][w * 1024 + 512]);
      gload_lds16(B + (size_t)(n0 + r0) * K + kb + c0, &Bs[cur ^ 1][w * 1024]);
      gload_lds16(B + (size_t)(n0 + r1) * K + kb + c1, &Bs[cur ^ 1][w * 1024 + 512]);
      asm volatile("s_waitcnt vmcnt(4)" ::: "memory");
    } else {
      asm volatile("s_waitcnt vmcnt(0)" ::: "memory");
    }
    __builtin_amdgcn_s_barrier();
    __builtin_amdgcn_sched_barrier(0);
    short8 af[8], bg[4];
#pragma unroll
    for (int m = 0; m < 8; ++m)
      af[m] = *(const short8*)&As[cur][(wr * 128 + m * 16 + lr) * 32 + lh * 8];
#pragma unroll
    for (int n = 0; n < 4; ++n)
      bg[n] = *(const short8*)&Bs[cur][(wc * 64 + n * 16 + lr) * 32 + lh * 8];
#pragma unroll
    for (int m = 0; m < 8; ++m)
#pragma unroll
      for (int n = 0; n < 4; ++n)
        acc[m][n] = __builtin_amdgcn_mfma_f32_16x16x32_bf16(af[m], bg[n], acc[m][n], 0, 0, 0);
    __builtin_amdgcn_s_barrier();
    __builtin_amdgcn_sched_barrier(0);
  }

  for (int m = 0; m < 8; ++m) {
    for (int n = 0; n < 4; ++n) {
      const int col = n0 + wc * 64 + n * 16 + lr;
      for (int r = 0; r < 4; ++r) {
        const int row = m0 + wr * 128 + m * 16 + lh * 4 + r;
        const size_t idx = (size_t)row * N + col;
        float v = acc[m][n][r];
        if (EPI == 0) {
          Cb[idx] = f2bf(v);
        } else {  // EPI == 2: relu(+bias)
          v += bias[col];
          Cb[idx] = f2bf(v > 0.f ? v : 0.f);
        }
      }
    }
  }
}

// ---------------- flash attention: QBLK=64, KVBLK=64, 4 waves ----------------
// Swapped QK^T (mfma(K,Q) -> S[kv][q], kv reduction lane-local), double-buffered
// K (LDS DMA) and V (reg-staged, async-split), counted vmcnt(4), setprio,
// cvt_pk bf16 packing, defer-max threshold, XCD swizzle.
__global__ __launch_bounds__(256) void k_attn(
    const unsigned short* __restrict__ qkv,
    unsigned short* __restrict__ outb)   // [token][1024]
{
  __shared__ unsigned short Qs[64 * 64];
  __shared__ unsigned short Ks[2][64 * 64];
  __shared__ unsigned short Vt[2][64 * 64];   // transposed+swizzled Vt[d][kv]
  __shared__ unsigned short Ps[4][16 * 72];

  const int t = threadIdx.x, lane = t & 63, w = t >> 6;
  // XCD swizzle: group 4 consecutive bh per XCD (KV 2MB fits 4MB L2)
  const int bid0 = blockIdx.y * 32 + blockIdx.x;
  const int swz = (bid0 & 7) * 128 + (bid0 >> 3);
  const int bh = swz >> 5;
  const int b = bh >> 4, h = bh & 15;
  const int q0 = (swz & 31) * 64;
  const size_t tokbase = (size_t)b * SEQ;
  const int qoff = h * 64, koff = 1024 + h * 64, voff = 2048 + h * 64;
  const int lr = lane & 15, lh = lane >> 4, lh4 = lh * 4;

  const int srow = lane >> 3;
  const int scol = (((lane & 7) ^ srow) & 7) << 3;

  gload_lds16(qkv + (tokbase + q0 + w * 16 + srow) * 3072 + qoff + scol, &Qs[w * 1024]);
  gload_lds16(qkv + (tokbase + q0 + w * 16 + 8 + srow) * 3072 + qoff + scol, &Qs[w * 1024 + 512]);
  gload_lds16(qkv + (tokbase + w * 16 + srow) * 3072 + koff + scol, &Ks[0][w * 1024]);
  gload_lds16(qkv + (tokbase + w * 16 + 8 + srow) * 3072 + koff + scol, &Ks[0][w * 1024 + 512]);

  const int kvr = t >> 2, d0v = (t & 3) * 16;
  const int vslotbase = (t & 3) * 2, kvslot = kvr >> 3, kvlow = kvr & 7;
  const int s0v = ((kvslot ^ vslotbase) & 7) << 3;
  const int s1v = ((kvslot ^ (vslotbase + 1)) & 7) << 3;

  ushort8 vA0, vA1, vB0, vB1;
  {
    const unsigned short* vsrc = qkv + (tokbase + kvr) * 3072 + voff + d0v;
    vA0 = *(const ushort8*)vsrc;
    vA1 = *(const ushort8*)(vsrc + 8);
  }
  asm volatile("s_waitcnt vmcnt(0)" ::: "memory");
  __builtin_amdgcn_s_barrier();
  __builtin_amdgcn_sched_barrier(0);

  const int qrow = w * 16 + lr;
  const short8 aq0 = *(const short8*)&Qs[qrow * 64 + (((lh ^ (lr & 7)) & 7) << 3)];
  const short8 aq1 = *(const short8*)&Qs[qrow * 64 + ((((lh + 4) ^ (lr & 7)) & 7) << 3)];

  int koffs0[4], koffs1[4], voffs0[4], voffs1[4];
  for (int nf = 0; nf < 4; ++nf) {
    const int krow = nf * 16 + lr;
    koffs0[nf] = krow * 64 + (((lh ^ (lr & 7)) & 7) << 3);
    koffs1[nf] = krow * 64 + ((((lh + 4) ^ (lr & 7)) & 7) << 3);
    const int d = nf * 16 + lr;
    const int key = (nf * 2 + (lr >> 3)) & 7;
    voffs0[nf] = d * 64 + (((lh ^ key) & 7) << 3);
    voffs1[nf] = d * 64 + ((((lh + 4) ^ key) & 7) << 3);
  }
  const unsigned short* pa0p = &Ps[w][lr * 72 + lh * 8];
  const unsigned short* pa1p = &Ps[w][lr * 72 + 32 + lh * 8];

  float m_run = -1e30f, l_run = 0.f;
  f32x4 oacc[4] = {};
  const float SCL = 0.125f * 1.44269504089f;  // head_scale * log2(e)

#define ATTN_STEP(CUR, VA0_, VA1_, VN0_, VN1_, KT)                                \
  {                                                                               \
    const int ktn = (KT) + 1;                                                     \
    if (ktn < NT) {                                                               \
      gload_lds16(qkv + (tokbase + ktn * 64 + w * 16 + srow) * 3072 + koff + scol,\
                  &Ks[1 - (CUR)][w * 1024]);                                      \
      gload_lds16(qkv + (tokbase + ktn * 64 + w * 16 + 8 + srow) * 3072 + koff + scol,\
                  &Ks[1 - (CUR)][w * 1024 + 512]);                                \
      const unsigned short* vsrc = qkv + (tokbase + ktn * 64 + kvr) * 3072 + voff + d0v;\
      VN0_ = *(const ushort8*)vsrc;                                               \
      VN1_ = *(const ushort8*)(vsrc + 8);                                         \
      asm volatile("s_waitcnt vmcnt(4)" ::: "memory");                            \
    } else {                                                                      \
      asm volatile("s_waitcnt vmcnt(0)" ::: "memory");                            \
    }                                                                             \
    __builtin_amdgcn_s_barrier();                                                 \
    __builtin_amdgcn_sched_barrier(0);                                            \
    for (int i = 0; i < 8; ++i) Vt[CUR][(d0v + i) * 64 + s0v + kvlow] = VA0_[i];  \
    for (int i = 0; i < 8; ++i) Vt[CUR][(d0v + 8 + i) * 64 + s1v + kvlow] = VA1_[i];\
    f32x4 sacc[4] = {};                                                           \
    __builtin_amdgcn_s_setprio(1);                                                \
    for (int nf = 0; nf < 4; ++nf) {                                              \
      short8 bk0 = *(const short8*)&Ks[CUR][koffs0[nf]];                          \
      short8 bk1 = *(const short8*)&Ks[CUR][koffs1[nf]];                          \
      sacc[nf] = __builtin_amdgcn_mfma_f32_16x16x32_bf16(bk0, aq0, sacc[nf], 0, 0, 0);\
      sacc[nf] = __builtin_amdgcn_mfma_f32_16x16x32_bf16(bk1, aq1, sacc[nf], 0, 0, 0);\
    }                                                                             \
    __builtin_amdgcn_s_setprio(0);                                                \
    /* max of 16 lane-local S values via max3-shaped tree */                      \
    float a0 = fmaxf(fmaxf(sacc[0][0], sacc[0][1]), sacc[0][2]);                  \
    float a1 = fmaxf(fmaxf(sacc[0][3], sacc[1][0]), sacc[1][1]);                  \
    float a2 = fmaxf(fmaxf(sacc[1][2], sacc[1][3]), sacc[2][0]);                  \
    float a3 = fmaxf(fmaxf(sacc[2][1], sacc[2][2]), sacc[2][3]);                  \
    float a4 = fmaxf(fmaxf(sacc[3][0], sacc[3][1]), sacc[3][2]);                  \
    float tm = fmaxf(fmaxf(fmaxf(a0, a1), fmaxf(a2, a3)), fmaxf(a4, sacc[3][3])); \
    tm *= SCL;                                                                    \
    tm = fmaxf(tm, __shfl_xor(tm, 16));                                           \
    tm = fmaxf(tm, __shfl_xor(tm, 32));                                           \
    if (__any(tm > m_run + 5.f)) {   /* defer-max: P bounded by 2^5 */            \
      const float mnew = fmaxf(m_run, tm);                                        \
      const float alpha = exp2f(m_run - mnew);                                    \
      m_run = mnew; l_run *= alpha;                                               \
      const float ar0 = __shfl(alpha, lh4 + 0), ar1 = __shfl(alpha, lh4 + 1);     \
      const float ar2 = __shfl(alpha, lh4 + 2), ar3 = __shfl(alpha, lh4 + 3);     \
      for (int nf = 0; nf < 4; ++nf) {                                            \
        oacc[nf][0] *= ar0; oacc[nf][1] *= ar1;                                   \
        oacc[nf][2] *= ar2; oacc[nf][3] *= ar3;                                   \
      }                                                                           \
    }                                                                             \
    float rs = 0.f;                                                               \
    for (int nf = 0; nf < 4; ++nf) {                                              \
      float p0 = exp2f(__builtin_fmaf(sacc[nf][0], SCL, -m_run));                 \
      float p1 = exp2f(__builtin_fmaf(sacc[nf][1], SCL, -m_run));                 \
      float p2 = exp2f(__builtin_fmaf(sacc[nf][2], SCL, -m_run));                 \
      float p3 = exp2f(__builtin_fmaf(sacc[nf][3], SCL, -m_run));                 \
      rs += (p0 + p1) + (p2 + p3);                                                \
      unsigned pk0, pk1;                                                          \
      asm("v_cvt_pk_bf16_f32 %0, %1, %2" : "=v"(pk0) : "v"(p0), "v"(p1));         \
      asm("v_cvt_pk_bf16_f32 %0, %1, %2" : "=v"(pk1) : "v"(p2), "v"(p3));         \
      uint2 pw; pw.x = pk0; pw.y = pk1;                                           \
      *(uint2*)&Ps[w][lr * 72 + nf * 16 + lh4] = pw;                              \
    }                                                                             \
    rs += __shfl_xor(rs, 16);                                                     \
    rs += __shfl_xor(rs, 32);                                                     \
    l_run += rs;                                                                  \
    short8 pa0 = *(const short8*)pa0p;                                            \
    short8 pa1 = *(const short8*)pa1p;                                            \
    asm volatile("s_waitcnt lgkmcnt(0)" ::: "memory");                            \
    __builtin_amdgcn_s_barrier();                                                 \
    __builtin_amdgcn_sched_barrier(0);                                            \
    __builtin_amdgcn_s_setprio(1);                                                \
    for (int nf = 0; nf < 4; ++nf) {                                              \
      short8 vb0 = *(const short8*)&Vt[CUR][voffs0[nf]];                          \
      short8 vb1 = *(const short8*)&Vt[CUR][voffs1[nf]];                          \
      oacc[nf] = __builtin_amdgcn_mfma_f32_16x16x32_bf16(pa0, vb0, oacc[nf], 0, 0, 0);\
      oacc[nf] = __builtin_amdgcn_mfma_f32_16x16x32_bf16(pa1, vb1, oacc[nf], 0, 0, 0);\
    }                                                                             \
    __builtin_amdgcn_s_setprio(0);                                                \
  }

  for (int kt2 = 0; kt2 < NT; kt2 += 2) {
    ATTN_STEP(0, vA0, vA1, vB0, vB1, kt2)
    ATTN_STEP(1, vB0, vB1, vA0, vA1, kt2 + 1)
  }
#undef ATTN_STEP

  const float lf0 = __shfl(l_run, lh4 + 0);
  const float lf1 = __shfl(l_run, lh4 + 1);
  const float lf2 = __shfl(l_run, lh4 + 2);
  const float lf3 = __shfl(l_run, lh4 + 3);
  const float ri0 = 1.f / lf0, ri1 = 1.f / lf1, ri2 = 1.f / lf2, ri3 = 1.f / lf3;
  for (int nf = 0; nf < 4; ++nf) {
    const int col = h * 64 + nf * 16 + lr;
    const size_t rowb = (tokbase + q0 + w * 16 + lh4) * (size_t)CMODEL + col;
    outb[rowb]               = f2bf(oacc[nf][0] * ri0);
    outb[rowb + CMODEL]      = f2bf(oacc[nf][1] * ri1);
    outb[rowb + 2 * CMODEL]  = f2bf(oacc[nf][2] * ri2);
    outb[rowb + 3 * CMODEL]  = f2bf(oacc[nf][3] * ri3);
  }
}

// ---------------- LayerNorm over rows of 1024 ----------------
template<int OUT_BF>
__global__ __launch_bounds__(256) void k_ln(const float* __restrict__ in,
    const float* __restrict__ g, const float* __restrict__ b,
    float* __restrict__ outf, unsigned short* __restrict__ outb)
{
  const int row = blockIdx.x;
  const int t = threadIdx.x;
  const float4* x4 = (const float4*)(in + (size_t)row * CMODEL);
  float4 v = x4[t];
  float s  = v.x + v.y + v.z + v.w;
  float s2 = v.x * v.x + v.y * v.y + v.z * v.z + v.w * v.w;
  for (int off = 32; off; off >>= 1) { s += __shfl_down(s, off); s2 += __shfl_down(s2, off); }
  __shared__ float red[8];
  __shared__ float stats[2];
  const int wv = t >> 6;
  if ((t & 63) == 0) { red[wv] = s; red[4 + wv] = s2; }
  __syncthreads();
  if (t == 0) {
    float ts  = red[0] + red[1] + red[2] + red[3];
    float ts2 = red[4] + red[5] + red[6] + red[7];
    float mu  = ts * (1.f / CMODEL);
    float var = ts2 * (1.f / CMODEL) - mu * mu;
    stats[0] = mu; stats[1] = rsqrtf(var + 1e-5f);
  }
  __syncthreads();
  const float mu = stats[0], rstd = stats[1];
  float4 gv = ((const float4*)g)[t];
  float4 bv = ((const float4*)b)[t];
  float o0 = (v.x - mu) * rstd * gv.x + bv.x;
  float o1 = (v.y - mu) * rstd * gv.y + bv.y;
  float o2 = (v.z - mu) * rstd * gv.z + bv.z;
  float o3 = (v.w - mu) * rstd * gv.w + bv.w;
  if (OUT_BF) {
    ushort4v o; o[0] = f2bf(o0); o[1] = f2bf(o1); o[2] = f2bf(o2); o[3] = f2bf(o3);
    ((ushort4v*)(outb + (size_t)row * CMODEL))[t] = o;
  } else {
    float4 o; o.x = o0; o.y = o1; o.z = o2; o.w = o3;
    ((float4*)(outf + (size_t)row * CMODEL))[t] = o;
  }
}

// ---------------- launch ----------------
extern "C" void kernel_launch(void* const* d_in, const int* in_sizes, int n_in,
                              void* d_out, int out_size, void* d_ws, size_t ws_size,
                              hipStream_t stream) {
  const float* src    = (const float*)d_in[0];
  const float* w_qkv  = (const float*)d_in[1];
  const float* w_proj = (const float*)d_in[2];
  const float* b_proj = (const float*)d_in[3];
  const float* w1     = (const float*)d_in[4];
  const float* b1     = (const float*)d_in[5];
  const float* w2     = (const float*)d_in[6];
  const float* b2     = (const float*)d_in[7];
  const float* g1     = (const float*)d_in[8];
  const float* be1    = (const float*)d_in[9];
  const float* g2     = (const float*)d_in[10];
  const float* be2    = (const float*)d_in[11];
  float* out = (float*)d_out;

  char* ws = (char*)d_ws;
  size_t off = 0;
  auto alloc = [&](size_t bytes) -> void* {
    void* p = ws + off;
    off += (bytes + 255) & ~(size_t)255;
    return p;
  };
  unsigned short* src_bf   = (unsigned short*)alloc((size_t)TOKENS * CMODEL * 2);
  unsigned short* wqkv_bf  = (unsigned short*)alloc((size_t)3 * CMODEL * CMODEL * 2);
  unsigned short* wproj_bf = (unsigned short*)alloc((size_t)CMODEL * CMODEL * 2);
  unsigned short* w1_bf    = (unsigned short*)alloc((size_t)DFF * CMODEL * 2);
  unsigned short* w2_bf    = (unsigned short*)alloc((size_t)CMODEL * DFF * 2);
  unsigned short* qkv_bf   = (unsigned short*)alloc((size_t)TOKENS * 3 * CMODEL * 2);
  unsigned short* attno_bf = (unsigned short*)alloc((size_t)TOKENS * CMODEL * 2);
  float*          z_f32    = (float*)alloc((size_t)TOKENS * CMODEL * 4);
  unsigned short* x_bf     = (unsigned short*)alloc((size_t)TOKENS * CMODEL * 2);
  unsigned short* h_bf     = (unsigned short*)alloc((size_t)TOKENS * DFF * 2);

  auto cvt = [&](const float* i, unsigned short* o, size_t n) {
    int n8 = (int)(n / 8);
    k_cvt<<<(n8 + 255) / 256, 256, 0, stream>>>(i, o, n8);
  };
  cvt(src,    src_bf,   (size_t)TOKENS * CMODEL);
  cvt(w_qkv,  wqkv_bf,  (size_t)3 * CMODEL * CMODEL);
  cvt(w_proj, wproj_bf, (size_t)CMODEL * CMODEL);
  cvt(w1,     w1_bf,    (size_t)DFF * CMODEL);
  cvt(w2,     w2_bf,    (size_t)CMODEL * DFF);

  // qkv = src @ w_qkv^T            [4096, 3072]  (256^2 tile)
  k_gemm256<0><<<dim3(3072 / 256, TOKENS / 256), 512, 0, stream>>>(
      src_bf, wqkv_bf, qkv_bf, nullptr, TOKENS, 3 * CMODEL, CMODEL);
  // attention -> attno             [4096, 1024]
  k_attn<<<dim3(SEQ / 64, 2 * HEADS), 256, 0, stream>>>(qkv_bf, attno_bf);
  // z = attno @ w_proj^T + b_proj + src   (f32)
  k_gemm_bt<1><<<dim3(CMODEL / 128, TOKENS / 128), 256, 0, stream>>>(
      attno_bf, wproj_bf, nullptr, z_f32, b_proj, src, nullptr, TOKENS, CMODEL, CMODEL);
  // x = LN1(z) -> bf16
  k_ln<1><<<TOKENS, 256, 0, stream>>>(z_f32, g1, be1, nullptr, x_bf);
  // h = relu(x @ w1^T + b1) -> bf16       [4096, 4096]  (256^2 tile)
  k_gemm256<2><<<dim3(DFF / 256, TOKENS / 256), 512, 0, stream>>>(
      x_bf, w1_bf, h_bf, b1, TOKENS, DFF, CMODEL);
  // z = h @ w2^T + b2 + x  (f32)
  k_gemm_bt<3><<<dim3(CMODEL / 128, TOKENS / 128), 256, 0, stream>>>(
      h_bf, w2_bf, nullptr, z_f32, b2, nullptr, x_bf, TOKENS, CMODEL, DFF);
  // out = LN2(z)
  k_ln<0><<<TOKENS, 256, 0, stream>>>(z_f32, g2, be2, out, nullptr);
}

// Round 6
// 393.263 us; speedup vs baseline: 1.3501x; 1.1115x over previous
//
#include <hip/hip_runtime.h>
#include <hip/hip_bf16.h>
#include <stdint.h>

// ---- problem constants ----
#define TOKENS 4096      // B*N = 2*2048
#define SEQ    2048
#define CMODEL 1024
#define HEADS  16
#define HDIM   64
#define DFF    4096
#define NT     (SEQ / 64)

typedef __attribute__((ext_vector_type(8))) short     short8;
typedef __attribute__((ext_vector_type(8))) unsigned short ushort8;
typedef __attribute__((ext_vector_type(4))) unsigned short ushort4v;
typedef __attribute__((ext_vector_type(4))) float     f32x4;

typedef const __attribute__((address_space(1))) void gbl_cvoid;
typedef __attribute__((address_space(3))) void lds_void;

__device__ inline unsigned short f2bf(float f) {
  unsigned int u = __builtin_bit_cast(unsigned int, f);
  u += 0x7fffu + ((u >> 16) & 1u);
  return (unsigned short)(u >> 16);
}
__device__ inline float bf2f(unsigned short h) {
  unsigned int u = ((unsigned int)h) << 16;
  return __builtin_bit_cast(float, u);
}

__device__ inline void gload_lds16(const unsigned short* g, unsigned short* lds) {
  __builtin_amdgcn_global_load_lds((gbl_cvoid*)g, (lds_void*)lds, 16, 0, 0);
}

// ---------------- fused f32 -> bf16 convert for all 5 tensors ----------------
// region boundaries in units of 8 elems
#define CVT_B0 524288    // src      4096*1024/8
#define CVT_B1 917504    // + w_qkv  3*1024*1024/8
#define CVT_B2 1048576   // + w_proj 1024*1024/8
#define CVT_B3 1572864   // + w1     4096*1024/8
#define CVT_B4 2097152   // + w2     1024*4096/8
__global__ __launch_bounds__(256) void k_cvt_all(
    const float* __restrict__ src, const float* __restrict__ wqkv,
    const float* __restrict__ wproj, const float* __restrict__ w1,
    const float* __restrict__ w2,
    unsigned short* __restrict__ o_src, unsigned short* __restrict__ o_wqkv,
    unsigned short* __restrict__ o_wproj, unsigned short* __restrict__ o_w1,
    unsigned short* __restrict__ o_w2)
{
  const int i = blockIdx.x * 256 + threadIdx.x;
  const float* in;
  unsigned short* out;
  int off;
  if (i < CVT_B0)      { in = src;   out = o_src;   off = i; }
  else if (i < CVT_B1) { in = wqkv;  out = o_wqkv;  off = i - CVT_B0; }
  else if (i < CVT_B2) { in = wproj; out = o_wproj; off = i - CVT_B1; }
  else if (i < CVT_B3) { in = w1;    out = o_w1;    off = i - CVT_B2; }
  else                 { in = w2;    out = o_w2;    off = i - CVT_B3; }
  const float4* p = (const float4*)in + 2 * (size_t)off;
  float4 a = p[0], b = p[1];
  ushort8 o;
  o[0] = f2bf(a.x); o[1] = f2bf(a.y); o[2] = f2bf(a.z); o[3] = f2bf(a.w);
  o[4] = f2bf(b.x); o[5] = f2bf(b.y); o[6] = f2bf(b.z); o[7] = f2bf(b.w);
  ((ushort8*)out)[off] = o;
}

// ---------------- bf16 BT-GEMM 128x128: C[M,N] = A[M,K] @ B[N,K]^T --------
// BK=32, 4 waves (2x2). 3-deep LDS pipeline: stage(kt+2), counted vmcnt(8).
// 48 KB LDS -> 3 blocks/CU.
// EPI: 0 = bf16 plain; 2 = bf16 relu(+bias); 4 = f32 partial (split-K via blockIdx.z)
template<int EPI>
__global__ __launch_bounds__(256) void k_gemm_bt(
    const unsigned short* __restrict__ A,
    const unsigned short* __restrict__ B,
    unsigned short* __restrict__ Cb,
    float* __restrict__ Cf,
    const float* __restrict__ bias,
    int M, int N, int K, int kspan)
{
  __shared__ unsigned short As[3][128 * 32];
  __shared__ unsigned short Bs[3][128 * 32];
  const int t = threadIdx.x;
  const int lane = t & 63;
  const int w = t >> 6;
  const int wr = w >> 1, wc = w & 1;
  // XCD-aware swizzle within the z-plane (plane nwg % 8 == 0 for all our grids)
  const int nwg = gridDim.x * gridDim.y;
  const int bid = blockIdx.y * gridDim.x + blockIdx.x;
  const int swz = (bid & 7) * (nwg >> 3) + (bid >> 3);
  const int n0 = (swz % gridDim.x) * 128;
  const int m0 = (swz / gridDim.x) * 128;
  const int kbase = blockIdx.z * kspan;

  const int e0 = w * 1024 + lane * 8;
  const int e1 = e0 + 512;
  const int r0 = e0 >> 5, c0 = e0 & 31;
  const int r1 = e1 >> 5, c1 = e1 & 31;

  f32x4 acc[4][4] = {};
  const int lr = lane & 15, lh = lane >> 4;
  const int nkt = kspan >> 5;

  auto stage = [&](int kt, int buf) {
    const int kb = kbase + (kt << 5);
    gload_lds16(A + (size_t)(m0 + r0) * K + kb + c0, &As[buf][w * 1024]);
    gload_lds16(A + (size_t)(m0 + r1) * K + kb + c1, &As[buf][w * 1024 + 512]);
    gload_lds16(B + (size_t)(n0 + r0) * K + kb + c0, &Bs[buf][w * 1024]);
    gload_lds16(B + (size_t)(n0 + r1) * K + kb + c1, &Bs[buf][w * 1024 + 512]);
  };
  stage(0, 0);
  if (nkt > 1) stage(1, 1);

  int buf = 0;
  for (int kt = 0; kt < nkt; ++kt) {
    if (kt + 2 < nkt) {
      const int nb = buf + 2 >= 3 ? buf - 1 : buf + 2;
      stage(kt + 2, nb);
      asm volatile("s_waitcnt vmcnt(8)" ::: "memory");   // kt landed; kt+1,kt+2 in flight
    } else if (kt + 1 < nkt) {
      asm volatile("s_waitcnt vmcnt(4)" ::: "memory");
    } else {
      asm volatile("s_waitcnt vmcnt(0)" ::: "memory");
    }
    __builtin_amdgcn_s_barrier();
    __builtin_amdgcn_sched_barrier(0);
    short8 af[4], bg[4];
#pragma unroll
    for (int m = 0; m < 4; ++m)
      af[m] = *(const short8*)&As[buf][(wr * 64 + m * 16 + lr) * 32 + lh * 8];
#pragma unroll
    for (int n = 0; n < 4; ++n)
      bg[n] = *(const short8*)&Bs[buf][(wc * 64 + n * 16 + lr) * 32 + lh * 8];
#pragma unroll
    for (int m = 0; m < 4; ++m)
#pragma unroll
      for (int n = 0; n < 4; ++n)
        acc[m][n] = __builtin_amdgcn_mfma_f32_16x16x32_bf16(af[m], bg[n], acc[m][n], 0, 0, 0);
    __builtin_amdgcn_s_barrier();   // readers done before DMA overwrites this buf
    __builtin_amdgcn_sched_barrier(0);
    buf = buf + 1 >= 3 ? 0 : buf + 1;
  }

  float* Cfp = (EPI == 4) ? Cf + (size_t)blockIdx.z * ((size_t)M * N) : Cf;
  for (int m = 0; m < 4; ++m) {
    for (int n = 0; n < 4; ++n) {
      const int col = n0 + wc * 64 + n * 16 + lr;
      for (int r = 0; r < 4; ++r) {
        const int row = m0 + wr * 64 + m * 16 + lh * 4 + r;
        const size_t idx = (size_t)row * N + col;
        float v = acc[m][n][r];
        if (EPI == 0) {
          Cb[idx] = f2bf(v);
        } else if (EPI == 2) {
          v += bias[col];
          Cb[idx] = f2bf(v > 0.f ? v : 0.f);
        } else {  // EPI == 4: f32 partial
          Cfp[idx] = v;
        }
      }
    }
  }
}

// ---------------- flash attention: QBLK=64, KVBLK=64, 4 waves ----------------
__global__ __launch_bounds__(256) void k_attn(
    const unsigned short* __restrict__ qkv,
    unsigned short* __restrict__ outb)   // [token][1024]
{
  __shared__ unsigned short Qs[64 * 64];
  __shared__ unsigned short Ks[2][64 * 64];
  __shared__ unsigned short Vt[2][64 * 64];   // transposed+swizzled Vt[d][kv]
  __shared__ unsigned short Ps[4][16 * 72];

  const int t = threadIdx.x, lane = t & 63, w = t >> 6;
  const int bid0 = blockIdx.y * 32 + blockIdx.x;
  const int swz = (bid0 & 7) * 128 + (bid0 >> 3);
  const int bh = swz >> 5;
  const int b = bh >> 4, h = bh & 15;
  const int q0 = (swz & 31) * 64;
  const size_t tokbase = (size_t)b * SEQ;
  const int qoff = h * 64, koff = 1024 + h * 64, voff = 2048 + h * 64;
  const int lr = lane & 15, lh = lane >> 4, lh4 = lh * 4;

  const int srow = lane >> 3;
  const int scol = (((lane & 7) ^ srow) & 7) << 3;

  gload_lds16(qkv + (tokbase + q0 + w * 16 + srow) * 3072 + qoff + scol, &Qs[w * 1024]);
  gload_lds16(qkv + (tokbase + q0 + w * 16 + 8 + srow) * 3072 + qoff + scol, &Qs[w * 1024 + 512]);
  gload_lds16(qkv + (tokbase + w * 16 + srow) * 3072 + koff + scol, &Ks[0][w * 1024]);
  gload_lds16(qkv + (tokbase + w * 16 + 8 + srow) * 3072 + koff + scol, &Ks[0][w * 1024 + 512]);

  const int kvr = t >> 2, d0v = (t & 3) * 16;
  const int vslotbase = (t & 3) * 2, kvslot = kvr >> 3, kvlow = kvr & 7;
  const int s0v = ((kvslot ^ vslotbase) & 7) << 3;
  const int s1v = ((kvslot ^ (vslotbase + 1)) & 7) << 3;

  ushort8 vA0, vA1, vB0, vB1;
  {
    const unsigned short* vsrc = qkv + (tokbase + kvr) * 3072 + voff + d0v;
    vA0 = *(const ushort8*)vsrc;
    vA1 = *(const ushort8*)(vsrc + 8);
  }
  asm volatile("s_waitcnt vmcnt(0)" ::: "memory");
  __builtin_amdgcn_s_barrier();
  __builtin_amdgcn_sched_barrier(0);

  const int qrow = w * 16 + lr;
  const short8 aq0 = *(const short8*)&Qs[qrow * 64 + (((lh ^ (lr & 7)) & 7) << 3)];
  const short8 aq1 = *(const short8*)&Qs[qrow * 64 + ((((lh + 4) ^ (lr & 7)) & 7) << 3)];

  int koffs0[4], koffs1[4], voffs0[4], voffs1[4];
  for (int nf = 0; nf < 4; ++nf) {
    const int krow = nf * 16 + lr;
    koffs0[nf] = krow * 64 + (((lh ^ (lr & 7)) & 7) << 3);
    koffs1[nf] = krow * 64 + ((((lh + 4) ^ (lr & 7)) & 7) << 3);
    const int d = nf * 16 + lr;
    const int key = (nf * 2 + (lr >> 3)) & 7;
    voffs0[nf] = d * 64 + (((lh ^ key) & 7) << 3);
    voffs1[nf] = d * 64 + ((((lh + 4) ^ key) & 7) << 3);
  }
  const unsigned short* pa0p = &Ps[w][lr * 72 + lh * 8];
  const unsigned short* pa1p = &Ps[w][lr * 72 + 32 + lh * 8];

  float m_run = -1e30f, l_run = 0.f;
  f32x4 oacc[4] = {};
  const float SCL = 0.125f * 1.44269504089f;  // head_scale * log2(e)

#define ATTN_STEP(CUR, VA0_, VA1_, VN0_, VN1_, KT)                                \
  {                                                                               \
    const int ktn = (KT) + 1;                                                     \
    if (ktn < NT) {                                                               \
      gload_lds16(qkv + (tokbase + ktn * 64 + w * 16 + srow) * 3072 + koff + scol,\
                  &Ks[1 - (CUR)][w * 1024]);                                      \
      gload_lds16(qkv + (tokbase + ktn * 64 + w * 16 + 8 + srow) * 3072 + koff + scol,\
                  &Ks[1 - (CUR)][w * 1024 + 512]);                                \
      const unsigned short* vsrc = qkv + (tokbase + ktn * 64 + kvr) * 3072 + voff + d0v;\
      VN0_ = *(const ushort8*)vsrc;                                               \
      VN1_ = *(const ushort8*)(vsrc + 8);                                         \
      asm volatile("s_waitcnt vmcnt(4)" ::: "memory");                            \
    } else {                                                                      \
      asm volatile("s_waitcnt vmcnt(0)" ::: "memory");                            \
    }                                                                             \
    __builtin_amdgcn_s_barrier();                                                 \
    __builtin_amdgcn_sched_barrier(0);                                            \
    for (int i = 0; i < 8; ++i) Vt[CUR][(d0v + i) * 64 + s0v + kvlow] = VA0_[i];  \
    for (int i = 0; i < 8; ++i) Vt[CUR][(d0v + 8 + i) * 64 + s1v + kvlow] = VA1_[i];\
    f32x4 sacc[4] = {};                                                           \
    __builtin_amdgcn_s_setprio(1);                                                \
    for (int nf = 0; nf < 4; ++nf) {                                              \
      short8 bk0 = *(const short8*)&Ks[CUR][koffs0[nf]];                          \
      short8 bk1 = *(const short8*)&Ks[CUR][koffs1[nf]];                          \
      sacc[nf] = __builtin_amdgcn_mfma_f32_16x16x32_bf16(bk0, aq0, sacc[nf], 0, 0, 0);\
      sacc[nf] = __builtin_amdgcn_mfma_f32_16x16x32_bf16(bk1, aq1, sacc[nf], 0, 0, 0);\
    }                                                                             \
    __builtin_amdgcn_s_setprio(0);                                                \
    float a0 = fmaxf(fmaxf(sacc[0][0], sacc[0][1]), sacc[0][2]);                  \
    float a1 = fmaxf(fmaxf(sacc[0][3], sacc[1][0]), sacc[1][1]);                  \
    float a2 = fmaxf(fmaxf(sacc[1][2], sacc[1][3]), sacc[2][0]);                  \
    float a3 = fmaxf(fmaxf(sacc[2][1], sacc[2][2]), sacc[2][3]);                  \
    float a4 = fmaxf(fmaxf(sacc[3][0], sacc[3][1]), sacc[3][2]);                  \
    float tm = fmaxf(fmaxf(fmaxf(a0, a1), fmaxf(a2, a3)), fmaxf(a4, sacc[3][3])); \
    tm *= SCL;                                                                    \
    tm = fmaxf(tm, __shfl_xor(tm, 16));                                           \
    tm = fmaxf(tm, __shfl_xor(tm, 32));                                           \
    if (__any(tm > m_run + 5.f)) {   /* defer-max: P bounded by 2^5 */            \
      const float mnew = fmaxf(m_run, tm);                                        \
      const float alpha = exp2f(m_run - mnew);                                    \
      m_run = mnew; l_run *= alpha;                                               \
      const float ar0 = __shfl(alpha, lh4 + 0), ar1 = __shfl(alpha, lh4 + 1);     \
      const float ar2 = __shfl(alpha, lh4 + 2), ar3 = __shfl(alpha, lh4 + 3);     \
      for (int nf = 0; nf < 4; ++nf) {                                            \
        oacc[nf][0] *= ar0; oacc[nf][1] *= ar1;                                   \
        oacc[nf][2] *= ar2; oacc[nf][3] *= ar3;                                   \
      }                                                                           \
    }                                                                             \
    float rs = 0.f;                                                               \
    for (int nf = 0; nf < 4; ++nf) {                                              \
      float p0 = exp2f(__builtin_fmaf(sacc[nf][0], SCL, -m_run));                 \
      float p1 = exp2f(__builtin_fmaf(sacc[nf][1], SCL, -m_run));                 \
      float p2 = exp2f(__builtin_fmaf(sacc[nf][2], SCL, -m_run));                 \
      float p3 = exp2f(__builtin_fmaf(sacc[nf][3], SCL, -m_run));                 \
      rs += (p0 + p1) + (p2 + p3);                                                \
      unsigned pk0, pk1;                                                          \
      asm("v_cvt_pk_bf16_f32 %0, %1, %2" : "=v"(pk0) : "v"(p0), "v"(p1));         \
      asm("v_cvt_pk_bf16_f32 %0, %1, %2" : "=v"(pk1) : "v"(p2), "v"(p3));         \
      uint2 pw; pw.x = pk0; pw.y = pk1;                                           \
      *(uint2*)&Ps[w][lr * 72 + nf * 16 + lh4] = pw;                              \
    }                                                                             \
    rs += __shfl_xor(rs, 16);                                                     \
    rs += __shfl_xor(rs, 32);                                                     \
    l_run += rs;                                                                  \
    short8 pa0 = *(const short8*)pa0p;                                            \
    short8 pa1 = *(const short8*)pa1p;                                            \
    asm volatile("s_waitcnt lgkmcnt(0)" ::: "memory");                            \
    __builtin_amdgcn_s_barrier();                                                 \
    __builtin_amdgcn_sched_barrier(0);                                            \
    __builtin_amdgcn_s_setprio(1);                                                \
    for (int nf = 0; nf < 4; ++nf) {                                              \
      short8 vb0 = *(const short8*)&Vt[CUR][voffs0[nf]];                          \
      short8 vb1 = *(const short8*)&Vt[CUR][voffs1[nf]];                          \
      oacc[nf] = __builtin_amdgcn_mfma_f32_16x16x32_bf16(pa0, vb0, oacc[nf], 0, 0, 0);\
      oacc[nf] = __builtin_amdgcn_mfma_f32_16x16x32_bf16(pa1, vb1, oacc[nf], 0, 0, 0);\
    }                                                                             \
    __builtin_amdgcn_s_setprio(0);                                                \
  }

  for (int kt2 = 0; kt2 < NT; kt2 += 2) {
    ATTN_STEP(0, vA0, vA1, vB0, vB1, kt2)
    ATTN_STEP(1, vB0, vB1, vA0, vA1, kt2 + 1)
  }
#undef ATTN_STEP

  const float lf0 = __shfl(l_run, lh4 + 0);
  const float lf1 = __shfl(l_run, lh4 + 1);
  const float lf2 = __shfl(l_run, lh4 + 2);
  const float lf3 = __shfl(l_run, lh4 + 3);
  const float ri0 = 1.f / lf0, ri1 = 1.f / lf1, ri2 = 1.f / lf2, ri3 = 1.f / lf3;
  for (int nf = 0; nf < 4; ++nf) {
    const int col = h * 64 + nf * 16 + lr;
    const size_t rowb = (tokbase + q0 + w * 16 + lh4) * (size_t)CMODEL + col;
    outb[rowb]               = f2bf(oacc[nf][0] * ri0);
    outb[rowb + CMODEL]      = f2bf(oacc[nf][1] * ri1);
    outb[rowb + 2 * CMODEL]  = f2bf(oacc[nf][2] * ri2);
    outb[rowb + 3 * CMODEL]  = f2bf(oacc[nf][3] * ri3);
  }
}

// ---------------- LN1: z = p0+p1+src+b_proj; x = LN(z)*g+b -> bf16 ----------
__global__ __launch_bounds__(256) void k_ln1(
    const float* __restrict__ p,      // [2][TOKENS][CMODEL]
    const float* __restrict__ src, const float* __restrict__ bias,
    const float* __restrict__ g, const float* __restrict__ b,
    unsigned short* __restrict__ xout)
{
  const int row = blockIdx.x;
  const int t = threadIdx.x;
  const size_t rb = (size_t)row * CMODEL;
  const float4 a0 = ((const float4*)(p + rb))[t];
  const float4 a1 = ((const float4*)(p + (size_t)TOKENS * CMODEL + rb))[t];
  const float4 sv = ((const float4*)(src + rb))[t];
  const float4 bb = ((const float4*)bias)[t];
  float4 v;
  v.x = a0.x + a1.x + sv.x + bb.x;
  v.y = a0.y + a1.y + sv.y + bb.y;
  v.z = a0.z + a1.z + sv.z + bb.z;
  v.w = a0.w + a1.w + sv.w + bb.w;
  float s  = v.x + v.y + v.z + v.w;
  float s2 = v.x * v.x + v.y * v.y + v.z * v.z + v.w * v.w;
  for (int off = 32; off; off >>= 1) { s += __shfl_down(s, off); s2 += __shfl_down(s2, off); }
  __shared__ float red[8];
  __shared__ float stats[2];
  const int wv = t >> 6;
  if ((t & 63) == 0) { red[wv] = s; red[4 + wv] = s2; }
  __syncthreads();
  if (t == 0) {
    float ts  = red[0] + red[1] + red[2] + red[3];
    float ts2 = red[4] + red[5] + red[6] + red[7];
    float mu  = ts * (1.f / CMODEL);
    float var = ts2 * (1.f / CMODEL) - mu * mu;
    stats[0] = mu; stats[1] = rsqrtf(var + 1e-5f);
  }
  __syncthreads();
  const float mu = stats[0], rstd = stats[1];
  float4 gv = ((const float4*)g)[t];
  float4 bv = ((const float4*)b)[t];
  ushort4v o;
  o[0] = f2bf((v.x - mu) * rstd * gv.x + bv.x);
  o[1] = f2bf((v.y - mu) * rstd * gv.y + bv.y);
  o[2] = f2bf((v.z - mu) * rstd * gv.z + bv.z);
  o[3] = f2bf((v.w - mu) * rstd * gv.w + bv.w);
  ((ushort4v*)(xout + rb))[t] = o;
}

// ---------------- LN2: z = q0+q1+x+b2; out = LN(z)*g+b -> f32 ----------------
__global__ __launch_bounds__(256) void k_ln2(
    const float* __restrict__ q,      // [2][TOKENS][CMODEL]
    const unsigned short* __restrict__ xres, const float* __restrict__ bias,
    const float* __restrict__ g, const float* __restrict__ b,
    float* __restrict__ out)
{
  const int row = blockIdx.x;
  const int t = threadIdx.x;
  const size_t rb = (size_t)row * CMODEL;
  const float4 a0 = ((const float4*)(q + rb))[t];
  const float4 a1 = ((const float4*)(q + (size_t)TOKENS * CMODEL + rb))[t];
  const ushort4v xv = ((const ushort4v*)(xres + rb))[t];
  const float4 bb = ((const float4*)bias)[t];
  float4 v;
  v.x = a0.x + a1.x + bf2f(xv[0]) + bb.x;
  v.y = a0.y + a1.y + bf2f(xv[1]) + bb.y;
  v.z = a0.z + a1.z + bf2f(xv[2]) + bb.z;
  v.w = a0.w + a1.w + bf2f(xv[3]) + bb.w;
  float s  = v.x + v.y + v.z + v.w;
  float s2 = v.x * v.x + v.y * v.y + v.z * v.z + v.w * v.w;
  for (int off = 32; off; off >>= 1) { s += __shfl_down(s, off); s2 += __shfl_down(s2, off); }
  __shared__ float red[8];
  __shared__ float stats[2];
  const int wv = t >> 6;
  if ((t & 63) == 0) { red[wv] = s; red[4 + wv] = s2; }
  __syncthreads();
  if (t == 0) {
    float ts  = red[0] + red[1] + red[2] + red[3];
    float ts2 = red[4] + red[5] + red[6] + red[7];
    float mu  = ts * (1.f / CMODEL);
    float var = ts2 * (1.f / CMODEL) - mu * mu;
    stats[0] = mu; stats[1] = rsqrtf(var + 1e-5f);
  }
  __syncthreads();
  const float mu = stats[0], rstd = stats[1];
  float4 gv = ((const float4*)g)[t];
  float4 bv = ((const float4*)b)[t];
  float4 o;
  o.x = (v.x - mu) * rstd * gv.x + bv.x;
  o.y = (v.y - mu) * rstd * gv.y + bv.y;
  o.z = (v.z - mu) * rstd * gv.z + bv.z;
  o.w = (v.w - mu) * rstd * gv.w + bv.w;
  ((float4*)(out + rb))[t] = o;
}

// ---------------- launch ----------------
extern "C" void kernel_launch(void* const* d_in, const int* in_sizes, int n_in,
                              void* d_out, int out_size, void* d_ws, size_t ws_size,
                              hipStream_t stream) {
  const float* src    = (const float*)d_in[0];
  const float* w_qkv  = (const float*)d_in[1];
  const float* w_proj = (const float*)d_in[2];
  const float* b_proj = (const float*)d_in[3];
  const float* w1     = (const float*)d_in[4];
  const float* b1     = (const float*)d_in[5];
  const float* w2     = (const float*)d_in[6];
  const float* b2     = (const float*)d_in[7];
  const float* g1     = (const float*)d_in[8];
  const float* be1    = (const float*)d_in[9];
  const float* g2     = (const float*)d_in[10];
  const float* be2    = (const float*)d_in[11];
  float* out = (float*)d_out;

  char* ws = (char*)d_ws;
  size_t off = 0;
  auto alloc = [&](size_t bytes) -> void* {
    void* p = ws + off;
    off += (bytes + 255) & ~(size_t)255;
    return p;
  };
  unsigned short* src_bf   = (unsigned short*)alloc((size_t)TOKENS * CMODEL * 2);      // 8 MB
  unsigned short* wqkv_bf  = (unsigned short*)alloc((size_t)3 * CMODEL * CMODEL * 2);  // 6 MB
  unsigned short* wproj_bf = (unsigned short*)alloc((size_t)CMODEL * CMODEL * 2);      // 2 MB
  unsigned short* w1_bf    = (unsigned short*)alloc((size_t)DFF * CMODEL * 2);         // 8 MB
  unsigned short* w2_bf    = (unsigned short*)alloc((size_t)CMODEL * DFF * 2);         // 8 MB
  unsigned short* x_bf     = (unsigned short*)alloc((size_t)TOKENS * CMODEL * 2);      // 8 MB
  unsigned short* h_bf     = (unsigned short*)alloc((size_t)TOKENS * DFF * 2);         // 32 MB
  // region R: qkv (24 MB) + attno (8 MB) + p_proj (32 MB) = 64 MB; p_ffn2 aliases R
  char* regionR = (char*)alloc((size_t)64 * 1024 * 1024);
  unsigned short* qkv_bf   = (unsigned short*)regionR;
  unsigned short* attno_bf = (unsigned short*)(regionR + (size_t)TOKENS * 3 * CMODEL * 2);
  float*          p_proj   = (float*)(regionR + (size_t)TOKENS * 3 * CMODEL * 2 + (size_t)TOKENS * CMODEL * 2);
  float*          p_ffn2   = (float*)regionR;   // [2][TOKENS][CMODEL] f32, alias (qkv/attno/p_proj dead)

  // 1. convert all inputs to bf16 (single kernel)
  k_cvt_all<<<CVT_B4 / 256, 256, 0, stream>>>(src, w_qkv, w_proj, w1, w2,
      src_bf, wqkv_bf, wproj_bf, w1_bf, w2_bf);
  // 2. qkv = src @ w_qkv^T            [4096, 3072]
  k_gemm_bt<0><<<dim3(3072 / 128, TOKENS / 128), 256, 0, stream>>>(
      src_bf, wqkv_bf, qkv_bf, nullptr, nullptr, TOKENS, 3 * CMODEL, CMODEL, CMODEL);
  // 3. attention -> attno             [4096, 1024]
  k_attn<<<dim3(SEQ / 64, 2 * HEADS), 256, 0, stream>>>(qkv_bf, attno_bf);
  // 4. p_proj[z] = attno @ w_proj^T (split-K2, f32 partials)
  k_gemm_bt<4><<<dim3(CMODEL / 128, TOKENS / 128, 2), 256, 0, stream>>>(
      attno_bf, wproj_bf, nullptr, p_proj, nullptr, TOKENS, CMODEL, CMODEL, CMODEL / 2);
  // 5. x = LN1(p0+p1+src+b_proj) -> bf16
  k_ln1<<<TOKENS, 256, 0, stream>>>(p_proj, src, b_proj, g1, be1, x_bf);
  // 6. h = relu(x @ w1^T + b1) -> bf16    [4096, 4096]
  k_gemm_bt<2><<<dim3(DFF / 128, TOKENS / 128), 256, 0, stream>>>(
      x_bf, w1_bf, h_bf, nullptr, b1, TOKENS, DFF, CMODEL, CMODEL);
  // 7. p_ffn2[z] = h @ w2^T (split-K2, f32 partials)
  k_gemm_bt<4><<<dim3(CMODEL / 128, TOKENS / 128, 2), 256, 0, stream>>>(
      h_bf, w2_bf, nullptr, p_ffn2, nullptr, TOKENS, CMODEL, DFF, DFF / 2);
  // 8. out = LN2(q0+q1+x+b2)
  k_ln2<<<TOKENS, 256, 0, stream>>>(p_ffn2, x_bf, b2, g2, be2, out);
}